// Round 12
// baseline (178.067 us; speedup 1.0000x reference)
//
#include <hip/hip_runtime.h>

typedef float f32x4 __attribute__((ext_vector_type(4)));
typedef float f32x16v __attribute__((ext_vector_type(16)));
typedef __bf16 bf16x4 __attribute__((ext_vector_type(4)));
typedef __bf16 bf16x8 __attribute__((ext_vector_type(8)));

union U4B8 { uint4 u; bf16x8 b; };

// ws layout (bf16 elements): b2p[9216] @0, b3p[36864] @9216, c1p[1024] @46080
#define B2P_OFF 0
#define B3P_OFF 9216
#define C1P_OFF 46080

// ------------------------------------------------------------- pack_weights
// b2p frag f=t*2+p: lane l, j: oc=l&31, ic=(l>>5)*8+j              (32x32x16)
// b3p frag f=t*8+nt*2+p: lane l, j: oc=nt*16+(l&15), ic=(l>>4)*8+j (16x16x32)
// c1p frag f in {Bh,Bl}: oc=l&15, k=(l>>4)*8+j, k = kx*9+ky*3+ic (<27), else 0
__global__ __launch_bounds__(256) void pack_weights(
    const float* __restrict__ w1, const float* __restrict__ w2,
    const float* __restrict__ w3, __bf16* __restrict__ wsb) {
  int i = blockIdx.x * 256 + threadIdx.x;
  if (i < 9216) {
    int f = i >> 9, r = i & 511;
    int l = r >> 3, j = r & 7;
    int t = f >> 1, p = f & 1;
    int ky = t / 3, kx = t % 3;
    int oc = l & 31, ic = ((l >> 5) << 3) + j;
    float v = w2[oc * 144 + ic * 9 + ky * 3 + kx];
    __bf16 hi = (__bf16)v;
    wsb[B2P_OFF + i] = p ? (__bf16)(v - (float)hi) : hi;
  } else if (i < 9216 + 36864) {
    int q = i - 9216;
    int f = q >> 9, r = q & 511;
    int l = r >> 3, j = r & 7;
    int t = f >> 3, nt = (f >> 1) & 3, p = f & 1;
    int ky = t / 3, kx = t % 3;
    int oc = nt * 16 + (l & 15), ic = ((l >> 4) << 3) + j;
    float v = w3[oc * 288 + ic * 9 + ky * 3 + kx];
    __bf16 hi = (__bf16)v;
    wsb[B3P_OFF + q] = p ? (__bf16)(v - (float)hi) : hi;
  } else if (i < 9216 + 36864 + 1024) {
    int q = i - (9216 + 36864);
    int f = q >> 9, r = q & 511;
    int l = r >> 3, j = r & 7;
    int oc = l & 15, k = ((l >> 4) << 3) + j;
    float v = 0.f;
    if (k < 27) {
      int kx = k / 9, rem = k % 9;
      int ky = rem / 3, ic = rem % 3;
      v = w1[oc * 27 + ic * 9 + ky * 3 + kx];
    }
    __bf16 hi = (__bf16)v;
    wsb[C1P_OFF + q] = f ? (__bf16)(v - (float)hi) : hi;
  }
}

// -------------------------------------------------------------- fused CNN
// 2 images/block, 4 waves. LDS union (32256 B peak):
//   phase1: s_img (2 x 9248B; cell = 4 ush [ic0,ic1,ic2,0])
//   phase2: s2 (2 x 16128B @0; 18 rows x 448 ush; cell 24 ush, hi only)
//   phase3: s3 (2 x 8960B @0; 10 rows x 448 ush; cell 40 ush, hi only)
//           h3s @17920 (2 x 4096B f32 [oc][py][px])
// launch_bounds (256,4): VGPR cap 128 — (256,8) caused scratch spill (R9).
__global__ __launch_bounds__(256, 4) void cnn_fused(
    const float* __restrict__ x, const __bf16* __restrict__ wsb,
    const float* __restrict__ b1, const float* __restrict__ b2,
    const float* __restrict__ b3,
    const float* __restrict__ fcw, const float* __restrict__ fcb,
    float* __restrict__ out) {
  __shared__ __align__(16) unsigned char smem[32256];
  __bf16* s_img = (__bf16*)smem;    // img k @ k*4624 ush
  __bf16* s2b   = (__bf16*)smem;    // img k @ k*8064 ush
  __bf16* s3b   = (__bf16*)smem;    // img k @ k*4480 ush
  float*  h3s   = (float*)(smem + 17920);  // img k @ k*1024 floats

  const __bf16* b2p = wsb + B2P_OFF;
  const __bf16* b3p = wsb + B3P_OFF;
  const __bf16* c1p = wsb + C1P_OFF;

  const int tid = threadIdx.x;
  const int img0 = blockIdx.x * 2;
  const int w = tid >> 6, lane = tid & 63;

  // ---- phase 1: zero s_img halos (132 cells x 2 = 264 > 256 -> LOOP,
  // R11's `if (tid < 264)` left 8 cells uninitialized -> garbage)
  for (int i = tid; i < 264; i += 256) {
    int ik = i >= 132, c = ik ? i - 132 : i;
    int row, col;
    if (c < 34)       { row = 0;       col = c; }
    else if (c < 68)  { row = 33;      col = c - 34; }
    else if (c < 100) { row = c - 67;  col = 0; }
    else              { row = c - 99;  col = 33; }
    *(unsigned long long*)&s_img[ik * 4624 + (row * 34 + col) * 4] = 0ull;
  }
  for (int i = tid; i < 2048; i += 256) {
    const int ik = i >> 10, rem = i & 1023;
    const int y = rem >> 5, xx = rem & 31;
    const float* xg = x + (img0 + ik) * 3072;
    bf16x4 pk;
    pk.x = (__bf16)xg[rem];
    pk.y = (__bf16)xg[rem + 1024];
    pk.z = (__bf16)xg[rem + 2048];
    pk.w = (__bf16)0.f;
    *(bf16x4*)&s_img[ik * 4624 + ((y + 1) * 34 + (xx + 1)) * 4] = pk;
  }
  const bf16x8 B1h = *(const bf16x8*)(c1p + lane * 8);
  const bf16x8 B1l = *(const bf16x8*)(c1p + 512 + lane * 8);
  __syncthreads();

  // ---- conv1: K=27-in-32 packed MFMA (R10-validated). 2 images.
  float pooled[2][16];
  {
    const int xm = lane & 15, kg = lane >> 4;
    #pragma unroll
    for (int ik = 0; ik < 2; ++ik) {
      const __bf16* si = s_img + ik * 4624;
      #pragma unroll
      for (int p = 0; p < 4; ++p) {
        f32x4 acc[2][2];
        #pragma unroll
        for (int ys = 0; ys < 2; ++ys)
          #pragma unroll
          for (int xh = 0; xh < 2; ++xh)
            #pragma unroll
            for (int r = 0; r < 4; ++r) acc[ys][xh][r] = 0.f;
        #pragma unroll
        for (int ys = 0; ys < 2; ++ys) {
          const int yqg = w * 8 + p * 2 + ys;
          #pragma unroll
          for (int xh = 0; xh < 2; ++xh) {
            const int xv = xh * 16 + xm;
            const int ca = xv + (kg <= 1 ? 0 : kg - 1);
            const int cb = xv + (kg < 2 ? 1 : 2);
            const uint2 qa0 = *(const uint2*)&si[((yqg + 0) * 34 + ca) * 4];
            const uint2 qa1 = *(const uint2*)&si[((yqg + 1) * 34 + ca) * 4];
            const uint2 qa2 = *(const uint2*)&si[((yqg + 2) * 34 + ca) * 4];
            const uint2 qb0 = *(const uint2*)&si[((yqg + 0) * 34 + cb) * 4];
            const uint2 qb1 = *(const uint2*)&si[((yqg + 1) * 34 + cb) * 4];
            const uint2 qb2 = *(const uint2*)&si[((yqg + 2) * 34 + cb) * 4];
            const uint a0 = qa0.x, a1 = qa0.y, a2 = qa1.x, a3 = qa1.y, a4 = qa2.x, a5 = qa2.y;
            const uint b0 = qb0.x, b1 = qb0.y, b2 = qb1.x, b3 = qb1.y, b4 = qb2.x;
            U4B8 A;
            A.u.x = kg == 0 ? a0
                  : kg == 1 ? (a5 | (b0 << 16))
                  : kg == 2 ? ((a4 >> 16) | (a5 << 16))
                  :           a4;
            A.u.y = kg == 0 ? (a1 | (a2 << 16))
                  : kg == 1 ? ((b0 >> 16) | (b1 << 16))
                  : kg == 2 ? b0
                  :           a5;
            A.u.z = kg == 0 ? ((a2 >> 16) | (a3 << 16))
                  : kg == 1 ? b2
                  : kg == 2 ? (b1 | (b2 << 16))
                  :           0u;
            A.u.w = kg == 0 ? a4
                  : kg == 1 ? (b3 | (b4 << 16))
                  : kg == 2 ? ((b2 >> 16) | (b3 << 16))
                  :           0u;
            acc[ys][xh] = __builtin_amdgcn_mfma_f32_16x16x32_bf16(A.b, B1h, acc[ys][xh], 0, 0, 0);
            acc[ys][xh] = __builtin_amdgcn_mfma_f32_16x16x32_bf16(A.b, B1l, acc[ys][xh], 0, 0, 0);
          }
        }
        #pragma unroll
        for (int xh = 0; xh < 2; ++xh)
          #pragma unroll
          for (int xp2 = 0; xp2 < 2; ++xp2) {
            const float v0 = fmaxf(acc[0][xh][xp2 * 2], acc[0][xh][xp2 * 2 + 1]);
            const float v1 = fmaxf(acc[1][xh][xp2 * 2], acc[1][xh][xp2 * 2 + 1]);
            pooled[ik][p * 4 + xh * 2 + xp2] = fmaxf(v0, v1);
          }
      }
    }
  }
  __syncthreads();   // s_img dead

  // ---- h1 (bias+relu, bf16 hi only) -> s2 (row stride 448, cell 24)
  if (tid < 136) {
    int ik = tid >= 68, c = ik ? tid - 68 : tid;
    int row, col;
    if (c < 18)      { row = 0;       col = c; }
    else if (c < 36) { row = 17;      col = c - 18; }
    else if (c < 52) { row = c - 35;  col = 0; }
    else             { row = c - 51;  col = 17; }
    unsigned long long* p = (unsigned long long*)&s2b[ik * 8064 + row * 448 + col * 24];
    p[0] = 0ull; p[1] = 0ull; p[2] = 0ull; p[3] = 0ull;
  }
  {
    const int oc = lane & 15, quad = lane >> 4;
    const float bias = b1[oc];
    #pragma unroll
    for (int ik = 0; ik < 2; ++ik)
      #pragma unroll
      for (int p = 0; p < 4; ++p)
        #pragma unroll
        for (int xh = 0; xh < 2; ++xh)
          #pragma unroll
          for (int xp2 = 0; xp2 < 2; ++xp2) {
            const float v = fmaxf(pooled[ik][p * 4 + xh * 2 + xp2] + bias, 0.f);
            const int py = w * 4 + p, px = xh * 8 + quad * 2 + xp2;
            s2b[ik * 8064 + (py + 1) * 448 + (px + 1) * 24 + oc] = (__bf16)v;
          }
  }
  bf16x8 Bf[18];
  #pragma unroll
  for (int f = 0; f < 18; ++f)
    Bf[f] = *(const bf16x8*)(b2p + f * 512 + lane * 8);
  __syncthreads();

  // ---- conv2 (2-term: a_h*(B_h+B_l)), stride-448, 2 images
  float pooled2[2][8];
  {
    const int xm = lane & 15, yoff = (lane >> 4) & 1, kh = lane >> 5;
    #pragma unroll
    for (int ik = 0; ik < 2; ++ik) {
      const unsigned short* s2 = (const unsigned short*)s2b + ik * 8064;
      f32x16v acc0, acc1;
      #pragma unroll
      for (int r = 0; r < 16; ++r) { acc0[r] = 0.f; acc1[r] = 0.f; }
      #pragma unroll
      for (int t = 0; t < 9; ++t) {
        const int ky = t / 3, kx = t % 3;
        const int col = (xm + kx) * 24 + kh * 8;
        const int row0 = (4 * w + yoff + ky) * 448 + col;
        const int row1 = row0 + 896;
        bf16x8 a0h = *(const bf16x8*)&s2[row0];
        bf16x8 a1h = *(const bf16x8*)&s2[row1];
        acc0 = __builtin_amdgcn_mfma_f32_32x32x16_bf16(a0h, Bf[t * 2],     acc0, 0, 0, 0);
        acc1 = __builtin_amdgcn_mfma_f32_32x32x16_bf16(a1h, Bf[t * 2],     acc1, 0, 0, 0);
        acc0 = __builtin_amdgcn_mfma_f32_32x32x16_bf16(a0h, Bf[t * 2 + 1], acc0, 0, 0, 0);
        acc1 = __builtin_amdgcn_mfma_f32_32x32x16_bf16(a1h, Bf[t * 2 + 1], acc1, 0, 0, 0);
      }
      #pragma unroll
      for (int i2 = 0; i2 < 2; ++i2) {
        const f32x16v& a = i2 ? acc1 : acc0;
        #pragma unroll
        for (int bq = 0; bq < 2; ++bq)
          #pragma unroll
          for (int rq = 0; rq < 2; ++rq) {
            const int r0 = bq * 4 + rq * 2;
            pooled2[ik][i2 * 4 + bq * 2 + rq] =
                fmaxf(fmaxf(a[r0], a[r0 + 1]), fmaxf(a[r0 + 8], a[r0 + 9]));
          }
      }
    }
  }
  __syncthreads();   // s2 dead

  // ---- h2 (bias+relu, bf16 hi only) -> s3 (row stride 448, cell 40)
  if (tid < 72) {
    int ik = tid >= 36, c = ik ? tid - 36 : tid;
    int row, col;
    if (c < 10)      { row = 0;       col = c; }
    else if (c < 20) { row = 9;       col = c - 10; }
    else if (c < 28) { row = c - 19;  col = 0; }
    else             { row = c - 27;  col = 9; }
    unsigned long long* p = (unsigned long long*)&s3b[ik * 4480 + row * 448 + col * 40];
    #pragma unroll
    for (int u = 0; u < 8; ++u) p[u] = 0ull;
  }
  {
    const int oc = lane & 31, hh = lane >> 5;
    const float bias = b2[oc];
    #pragma unroll
    for (int ik = 0; ik < 2; ++ik)
      #pragma unroll
      for (int i2 = 0; i2 < 2; ++i2)
        #pragma unroll
        for (int bq = 0; bq < 2; ++bq)
          #pragma unroll
          for (int rq = 0; rq < 2; ++rq) {
            const float v = fmaxf(pooled2[ik][i2 * 4 + bq * 2 + rq] + bias, 0.f);
            const int py = 2 * w + i2, px = 2 * hh + 4 * bq + rq;
            s3b[ik * 4480 + (py + 1) * 448 + (px + 1) * 40 + oc] = (__bf16)v;
          }
  }
  __syncthreads();

  // ---- conv3 (wave = nt = oc-tile), 2-term, 2 images
  {
    const int nt = w;
    bf16x8 Bt[18];
    #pragma unroll
    for (int t = 0; t < 9; ++t) {
      Bt[t * 2]     = *(const bf16x8*)(b3p + (t * 8 + nt * 2) * 512 + lane * 8);
      Bt[t * 2 + 1] = *(const bf16x8*)(b3p + (t * 8 + nt * 2 + 1) * 512 + lane * 8);
    }
    const int m = lane & 15, quad = lane >> 4;
    const int xm = m & 7, yoff = m >> 3;
    const int ocl = lane & 15;
    #pragma unroll
    for (int ik = 0; ik < 2; ++ik) {
      const unsigned short* s3 = (const unsigned short*)s3b + ik * 4480;
      f32x4 acc[4];
      #pragma unroll
      for (int mt = 0; mt < 4; ++mt)
        #pragma unroll
        for (int r = 0; r < 4; ++r) acc[mt][r] = 0.f;
      #pragma unroll
      for (int t = 0; t < 9; ++t) {
        const int ky = t / 3, kx = t % 3;
        #pragma unroll
        for (int mt = 0; mt < 4; ++mt) {
          const int ro = (2 * mt + yoff + ky) * 448 + (xm + kx) * 40 + quad * 8;
          bf16x8 ah = *(const bf16x8*)&s3[ro];
          acc[mt] = __builtin_amdgcn_mfma_f32_16x16x32_bf16(ah, Bt[t * 2],     acc[mt], 0, 0, 0);
          acc[mt] = __builtin_amdgcn_mfma_f32_16x16x32_bf16(ah, Bt[t * 2 + 1], acc[mt], 0, 0, 0);
        }
      }
      #pragma unroll
      for (int mt = 0; mt < 4; ++mt) {
        float p0 = fmaxf(acc[mt][0], acc[mt][1]);
        float p1 = fmaxf(acc[mt][2], acc[mt][3]);
        p0 = fmaxf(p0, __shfl_xor(p0, 32, 64));
        p1 = fmaxf(p1, __shfl_xor(p1, 32, 64));
        if (quad < 2) {
          const int oc = nt * 16 + ocl;
          const float bias = b3[oc];
          const int base = ik * 1024 + oc * 16 + mt * 4 + (quad & 1) * 2;
          h3s[base]     = fmaxf(p0 + bias, 0.f);
          h3s[base + 1] = fmaxf(p1 + bias, 0.f);
        }
      }
    }
  }
  __syncthreads();

  // ---- fc: wave 0 -> image 0, wave 1 -> image 1
  if (w < 2) {
    const float* h = h3s + w * 1024;
    float hv[16];
    #pragma unroll
    for (int i = 0; i < 16; ++i) hv[i] = h[i * 64 + lane];
    #pragma unroll
    for (int j = 0; j < 10; ++j) {
      float dot = 0.f;
      #pragma unroll
      for (int i = 0; i < 16; ++i)
        dot = fmaf(hv[i], fcw[j * 1024 + i * 64 + lane], dot);
      #pragma unroll
      for (int s = 32; s > 0; s >>= 1) dot += __shfl_xor(dot, s, 64);
      if (lane == 0) out[(img0 + w) * 10 + j] = dot + fcb[j];
    }
  }
}

// -------------------------------------------------------------------- launch
extern "C" void kernel_launch(void* const* d_in, const int* in_sizes, int n_in,
                              void* d_out, int out_size, void* d_ws, size_t ws_size,
                              hipStream_t stream) {
  const float* x   = (const float*)d_in[0];
  const float* w1  = (const float*)d_in[1];
  const float* b1  = (const float*)d_in[2];
  const float* w2  = (const float*)d_in[3];
  const float* b2  = (const float*)d_in[4];
  const float* w3  = (const float*)d_in[5];
  const float* b3  = (const float*)d_in[6];
  const float* fcw = (const float*)d_in[7];
  const float* fcb = (const float*)d_in[8];
  __bf16* wsb = (__bf16*)d_ws;
  float* out = (float*)d_out;

  hipLaunchKernelGGL(pack_weights, dim3(184), dim3(256), 0, stream, w1, w2, w3, wsb);
  hipLaunchKernelGGL(cnn_fused, dim3(2048), dim3(256), 0, stream,
                     x, wsb, b1, b2, b3, fcw, fcb, out);
}

// Round 13
// 162.852 us; speedup vs baseline: 1.0934x; 1.0934x over previous
//
#include <hip/hip_runtime.h>

typedef float f32x4 __attribute__((ext_vector_type(4)));
typedef float f32x16v __attribute__((ext_vector_type(16)));
typedef __bf16 bf16x4 __attribute__((ext_vector_type(4)));
typedef __bf16 bf16x8 __attribute__((ext_vector_type(8)));

union U4B8 { uint4 u; bf16x8 b; };

// ws layout (bf16 elements): b2p[9216] @0, b3p[36864] @9216, c1p[1024] @46080
#define B2P_OFF 0
#define B3P_OFF 9216
#define C1P_OFF 46080

// ------------------------------------------------------------- pack_weights
// b2p frag f=t*2+p: lane l, j: oc=l&31, ic=(l>>5)*8+j              (32x32x16)
// b3p frag f=t*8+nt*2+p: lane l, j: oc=nt*16+(l&15), ic=(l>>4)*8+j (16x16x32)
// c1p frag f in {Bh,Bl}: oc=l&15, k=(l>>4)*8+j, k = kx*9+ky*3+ic (<27), else 0
__global__ __launch_bounds__(256) void pack_weights(
    const float* __restrict__ w1, const float* __restrict__ w2,
    const float* __restrict__ w3, __bf16* __restrict__ wsb) {
  int i = blockIdx.x * 256 + threadIdx.x;
  if (i < 9216) {
    int f = i >> 9, r = i & 511;
    int l = r >> 3, j = r & 7;
    int t = f >> 1, p = f & 1;
    int ky = t / 3, kx = t % 3;
    int oc = l & 31, ic = ((l >> 5) << 3) + j;
    float v = w2[oc * 144 + ic * 9 + ky * 3 + kx];
    __bf16 hi = (__bf16)v;
    wsb[B2P_OFF + i] = p ? (__bf16)(v - (float)hi) : hi;
  } else if (i < 9216 + 36864) {
    int q = i - 9216;
    int f = q >> 9, r = q & 511;
    int l = r >> 3, j = r & 7;
    int t = f >> 3, nt = (f >> 1) & 3, p = f & 1;
    int ky = t / 3, kx = t % 3;
    int oc = nt * 16 + (l & 15), ic = ((l >> 4) << 3) + j;
    float v = w3[oc * 288 + ic * 9 + ky * 3 + kx];
    __bf16 hi = (__bf16)v;
    wsb[B3P_OFF + q] = p ? (__bf16)(v - (float)hi) : hi;
  } else if (i < 9216 + 36864 + 1024) {
    int q = i - (9216 + 36864);
    int f = q >> 9, r = q & 511;
    int l = r >> 3, j = r & 7;
    int oc = l & 15, k = ((l >> 4) << 3) + j;
    float v = 0.f;
    if (k < 27) {
      int kx = k / 9, rem = k % 9;
      int ky = rem / 3, ic = rem % 3;
      v = w1[oc * 27 + ic * 9 + ky * 3 + kx];
    }
    __bf16 hi = (__bf16)v;
    wsb[C1P_OFF + q] = f ? (__bf16)(v - (float)hi) : hi;
  }
}

// -------------------------------------------------------------- fused CNN
// 2 images/block, 4 waves. LDS union (32256 B peak -> 4 blocks/CU):
//   phase1: s_img (2 x 9248B; cell = 4 ush [ic0,ic1,ic2,0])
//   phase2: s2 (2 x 16128B @0; 18 rows x 448 ush; cell 24 ush, hi only)
//   phase3: s3 (2 x 8960B @0; 10 rows x 448 ush; cell 40 ush, hi only)
//           h3s @17920 (2 x 4096B f32 [oc][py][px])
// launch_bounds (256,2): empirical reg budget ~512/(2*minwaves):
//   (256,8)->32 regs (R9 spill), (256,4)->64 (R12 spill with 2-img state),
//   (256,3)->76. (256,2) -> ~128, matching the 4-waves/SIMD LDS limit.
__global__ __launch_bounds__(256, 2) void cnn_fused(
    const float* __restrict__ x, const __bf16* __restrict__ wsb,
    const float* __restrict__ b1, const float* __restrict__ b2,
    const float* __restrict__ b3,
    const float* __restrict__ fcw, const float* __restrict__ fcb,
    float* __restrict__ out) {
  __shared__ __align__(16) unsigned char smem[32256];
  __bf16* s_img = (__bf16*)smem;    // img k @ k*4624 ush
  __bf16* s2b   = (__bf16*)smem;    // img k @ k*8064 ush
  __bf16* s3b   = (__bf16*)smem;    // img k @ k*4480 ush
  float*  h3s   = (float*)(smem + 17920);  // img k @ k*1024 floats

  const __bf16* b2p = wsb + B2P_OFF;
  const __bf16* b3p = wsb + B3P_OFF;
  const __bf16* c1p = wsb + C1P_OFF;

  const int tid = threadIdx.x;
  const int img0 = blockIdx.x * 2;
  const int w = tid >> 6, lane = tid & 63;

  // ---- phase 1: zero s_img halos (132 cells x 2 = 264 -> loop)
  for (int i = tid; i < 264; i += 256) {
    int ik = i >= 132, c = ik ? i - 132 : i;
    int row, col;
    if (c < 34)       { row = 0;       col = c; }
    else if (c < 68)  { row = 33;      col = c - 34; }
    else if (c < 100) { row = c - 67;  col = 0; }
    else              { row = c - 99;  col = 33; }
    *(unsigned long long*)&s_img[ik * 4624 + (row * 34 + col) * 4] = 0ull;
  }
  for (int i = tid; i < 2048; i += 256) {
    const int ik = i >> 10, rem = i & 1023;
    const int y = rem >> 5, xx = rem & 31;
    const float* xg = x + (img0 + ik) * 3072;
    bf16x4 pk;
    pk.x = (__bf16)xg[rem];
    pk.y = (__bf16)xg[rem + 1024];
    pk.z = (__bf16)xg[rem + 2048];
    pk.w = (__bf16)0.f;
    *(bf16x4*)&s_img[ik * 4624 + ((y + 1) * 34 + (xx + 1)) * 4] = pk;
  }
  const bf16x8 B1h = *(const bf16x8*)(c1p + lane * 8);
  const bf16x8 B1l = *(const bf16x8*)(c1p + 512 + lane * 8);
  __syncthreads();

  // ---- conv1: K=27-in-32 packed MFMA (R10-validated). 2 images.
  float pooled[2][16];
  {
    const int xm = lane & 15, kg = lane >> 4;
    #pragma unroll
    for (int ik = 0; ik < 2; ++ik) {
      const __bf16* si = s_img + ik * 4624;
      #pragma unroll
      for (int p = 0; p < 4; ++p) {
        f32x4 acc[2][2];
        #pragma unroll
        for (int ys = 0; ys < 2; ++ys)
          #pragma unroll
          for (int xh = 0; xh < 2; ++xh)
            #pragma unroll
            for (int r = 0; r < 4; ++r) acc[ys][xh][r] = 0.f;
        #pragma unroll
        for (int ys = 0; ys < 2; ++ys) {
          const int yqg = w * 8 + p * 2 + ys;
          #pragma unroll
          for (int xh = 0; xh < 2; ++xh) {
            const int xv = xh * 16 + xm;
            const int ca = xv + (kg <= 1 ? 0 : kg - 1);
            const int cb = xv + (kg < 2 ? 1 : 2);
            const uint2 qa0 = *(const uint2*)&si[((yqg + 0) * 34 + ca) * 4];
            const uint2 qa1 = *(const uint2*)&si[((yqg + 1) * 34 + ca) * 4];
            const uint2 qa2 = *(const uint2*)&si[((yqg + 2) * 34 + ca) * 4];
            const uint2 qb0 = *(const uint2*)&si[((yqg + 0) * 34 + cb) * 4];
            const uint2 qb1 = *(const uint2*)&si[((yqg + 1) * 34 + cb) * 4];
            const uint2 qb2 = *(const uint2*)&si[((yqg + 2) * 34 + cb) * 4];
            const uint a0 = qa0.x, a1 = qa0.y, a2 = qa1.x, a3 = qa1.y, a4 = qa2.x, a5 = qa2.y;
            const uint b0 = qb0.x, b1 = qb0.y, b2 = qb1.x, b3 = qb1.y, b4 = qb2.x;
            U4B8 A;
            A.u.x = kg == 0 ? a0
                  : kg == 1 ? (a5 | (b0 << 16))
                  : kg == 2 ? ((a4 >> 16) | (a5 << 16))
                  :           a4;
            A.u.y = kg == 0 ? (a1 | (a2 << 16))
                  : kg == 1 ? ((b0 >> 16) | (b1 << 16))
                  : kg == 2 ? b0
                  :           a5;
            A.u.z = kg == 0 ? ((a2 >> 16) | (a3 << 16))
                  : kg == 1 ? b2
                  : kg == 2 ? (b1 | (b2 << 16))
                  :           0u;
            A.u.w = kg == 0 ? a4
                  : kg == 1 ? (b3 | (b4 << 16))
                  : kg == 2 ? ((b2 >> 16) | (b3 << 16))
                  :           0u;
            acc[ys][xh] = __builtin_amdgcn_mfma_f32_16x16x32_bf16(A.b, B1h, acc[ys][xh], 0, 0, 0);
            acc[ys][xh] = __builtin_amdgcn_mfma_f32_16x16x32_bf16(A.b, B1l, acc[ys][xh], 0, 0, 0);
          }
        }
        #pragma unroll
        for (int xh = 0; xh < 2; ++xh)
          #pragma unroll
          for (int xp2 = 0; xp2 < 2; ++xp2) {
            const float v0 = fmaxf(acc[0][xh][xp2 * 2], acc[0][xh][xp2 * 2 + 1]);
            const float v1 = fmaxf(acc[1][xh][xp2 * 2], acc[1][xh][xp2 * 2 + 1]);
            pooled[ik][p * 4 + xh * 2 + xp2] = fmaxf(v0, v1);
          }
      }
    }
  }
  __syncthreads();   // s_img dead

  // ---- h1 (bias+relu, bf16 hi only) -> s2 (row stride 448, cell 24)
  if (tid < 136) {
    int ik = tid >= 68, c = ik ? tid - 68 : tid;
    int row, col;
    if (c < 18)      { row = 0;       col = c; }
    else if (c < 36) { row = 17;      col = c - 18; }
    else if (c < 52) { row = c - 35;  col = 0; }
    else             { row = c - 51;  col = 17; }
    unsigned long long* p = (unsigned long long*)&s2b[ik * 8064 + row * 448 + col * 24];
    p[0] = 0ull; p[1] = 0ull; p[2] = 0ull; p[3] = 0ull;
  }
  {
    const int oc = lane & 15, quad = lane >> 4;
    const float bias = b1[oc];
    #pragma unroll
    for (int ik = 0; ik < 2; ++ik)
      #pragma unroll
      for (int p = 0; p < 4; ++p)
        #pragma unroll
        for (int xh = 0; xh < 2; ++xh)
          #pragma unroll
          for (int xp2 = 0; xp2 < 2; ++xp2) {
            const float v = fmaxf(pooled[ik][p * 4 + xh * 2 + xp2] + bias, 0.f);
            const int py = w * 4 + p, px = xh * 8 + quad * 2 + xp2;
            s2b[ik * 8064 + (py + 1) * 448 + (px + 1) * 24 + oc] = (__bf16)v;
          }
  }
  bf16x8 Bf[18];
  #pragma unroll
  for (int f = 0; f < 18; ++f)
    Bf[f] = *(const bf16x8*)(b2p + f * 512 + lane * 8);
  __syncthreads();

  // ---- conv2 (2-term: a_h*(B_h+B_l)), stride-448, 2 images
  float pooled2[2][8];
  {
    const int xm = lane & 15, yoff = (lane >> 4) & 1, kh = lane >> 5;
    #pragma unroll
    for (int ik = 0; ik < 2; ++ik) {
      const unsigned short* s2 = (const unsigned short*)s2b + ik * 8064;
      f32x16v acc0, acc1;
      #pragma unroll
      for (int r = 0; r < 16; ++r) { acc0[r] = 0.f; acc1[r] = 0.f; }
      #pragma unroll
      for (int t = 0; t < 9; ++t) {
        const int ky = t / 3, kx = t % 3;
        const int col = (xm + kx) * 24 + kh * 8;
        const int row0 = (4 * w + yoff + ky) * 448 + col;
        const int row1 = row0 + 896;
        bf16x8 a0h = *(const bf16x8*)&s2[row0];
        bf16x8 a1h = *(const bf16x8*)&s2[row1];
        acc0 = __builtin_amdgcn_mfma_f32_32x32x16_bf16(a0h, Bf[t * 2],     acc0, 0, 0, 0);
        acc1 = __builtin_amdgcn_mfma_f32_32x32x16_bf16(a1h, Bf[t * 2],     acc1, 0, 0, 0);
        acc0 = __builtin_amdgcn_mfma_f32_32x32x16_bf16(a0h, Bf[t * 2 + 1], acc0, 0, 0, 0);
        acc1 = __builtin_amdgcn_mfma_f32_32x32x16_bf16(a1h, Bf[t * 2 + 1], acc1, 0, 0, 0);
      }
      #pragma unroll
      for (int i2 = 0; i2 < 2; ++i2) {
        const f32x16v& a = i2 ? acc1 : acc0;
        #pragma unroll
        for (int bq = 0; bq < 2; ++bq)
          #pragma unroll
          for (int rq = 0; rq < 2; ++rq) {
            const int r0 = bq * 4 + rq * 2;
            pooled2[ik][i2 * 4 + bq * 2 + rq] =
                fmaxf(fmaxf(a[r0], a[r0 + 1]), fmaxf(a[r0 + 8], a[r0 + 9]));
          }
      }
    }
  }
  __syncthreads();   // s2 dead

  // ---- h2 (bias+relu, bf16 hi only) -> s3 (row stride 448, cell 40)
  if (tid < 72) {
    int ik = tid >= 36, c = ik ? tid - 36 : tid;
    int row, col;
    if (c < 10)      { row = 0;       col = c; }
    else if (c < 20) { row = 9;       col = c - 10; }
    else if (c < 28) { row = c - 19;  col = 0; }
    else             { row = c - 27;  col = 9; }
    unsigned long long* p = (unsigned long long*)&s3b[ik * 4480 + row * 448 + col * 40];
    #pragma unroll
    for (int u = 0; u < 8; ++u) p[u] = 0ull;
  }
  {
    const int oc = lane & 31, hh = lane >> 5;
    const float bias = b2[oc];
    #pragma unroll
    for (int ik = 0; ik < 2; ++ik)
      #pragma unroll
      for (int i2 = 0; i2 < 2; ++i2)
        #pragma unroll
        for (int bq = 0; bq < 2; ++bq)
          #pragma unroll
          for (int rq = 0; rq < 2; ++rq) {
            const float v = fmaxf(pooled2[ik][i2 * 4 + bq * 2 + rq] + bias, 0.f);
            const int py = 2 * w + i2, px = 2 * hh + 4 * bq + rq;
            s3b[ik * 4480 + (py + 1) * 448 + (px + 1) * 40 + oc] = (__bf16)v;
          }
  }
  __syncthreads();

  // ---- conv3 (wave = nt = oc-tile), 2-term, 2 images
  {
    const int nt = w;
    bf16x8 Bt[18];
    #pragma unroll
    for (int t = 0; t < 9; ++t) {
      Bt[t * 2]     = *(const bf16x8*)(b3p + (t * 8 + nt * 2) * 512 + lane * 8);
      Bt[t * 2 + 1] = *(const bf16x8*)(b3p + (t * 8 + nt * 2 + 1) * 512 + lane * 8);
    }
    const int m = lane & 15, quad = lane >> 4;
    const int xm = m & 7, yoff = m >> 3;
    const int ocl = lane & 15;
    #pragma unroll
    for (int ik = 0; ik < 2; ++ik) {
      const unsigned short* s3 = (const unsigned short*)s3b + ik * 4480;
      f32x4 acc[4];
      #pragma unroll
      for (int mt = 0; mt < 4; ++mt)
        #pragma unroll
        for (int r = 0; r < 4; ++r) acc[mt][r] = 0.f;
      #pragma unroll
      for (int t = 0; t < 9; ++t) {
        const int ky = t / 3, kx = t % 3;
        #pragma unroll
        for (int mt = 0; mt < 4; ++mt) {
          const int ro = (2 * mt + yoff + ky) * 448 + (xm + kx) * 40 + quad * 8;
          bf16x8 ah = *(const bf16x8*)&s3[ro];
          acc[mt] = __builtin_amdgcn_mfma_f32_16x16x32_bf16(ah, Bt[t * 2],     acc[mt], 0, 0, 0);
          acc[mt] = __builtin_amdgcn_mfma_f32_16x16x32_bf16(ah, Bt[t * 2 + 1], acc[mt], 0, 0, 0);
        }
      }
      #pragma unroll
      for (int mt = 0; mt < 4; ++mt) {
        float p0 = fmaxf(acc[mt][0], acc[mt][1]);
        float p1 = fmaxf(acc[mt][2], acc[mt][3]);
        p0 = fmaxf(p0, __shfl_xor(p0, 32, 64));
        p1 = fmaxf(p1, __shfl_xor(p1, 32, 64));
        if (quad < 2) {
          const int oc = nt * 16 + ocl;
          const float bias = b3[oc];
          const int base = ik * 1024 + oc * 16 + mt * 4 + (quad & 1) * 2;
          h3s[base]     = fmaxf(p0 + bias, 0.f);
          h3s[base + 1] = fmaxf(p1 + bias, 0.f);
        }
      }
    }
  }
  __syncthreads();

  // ---- fc: wave 0 -> image 0, wave 1 -> image 1
  if (w < 2) {
    const float* h = h3s + w * 1024;
    float hv[16];
    #pragma unroll
    for (int i = 0; i < 16; ++i) hv[i] = h[i * 64 + lane];
    #pragma unroll
    for (int j = 0; j < 10; ++j) {
      float dot = 0.f;
      #pragma unroll
      for (int i = 0; i < 16; ++i)
        dot = fmaf(hv[i], fcw[j * 1024 + i * 64 + lane], dot);
      #pragma unroll
      for (int s = 32; s > 0; s >>= 1) dot += __shfl_xor(dot, s, 64);
      if (lane == 0) out[(img0 + w) * 10 + j] = dot + fcb[j];
    }
  }
}

// -------------------------------------------------------------------- launch
extern "C" void kernel_launch(void* const* d_in, const int* in_sizes, int n_in,
                              void* d_out, int out_size, void* d_ws, size_t ws_size,
                              hipStream_t stream) {
  const float* x   = (const float*)d_in[0];
  const float* w1  = (const float*)d_in[1];
  const float* b1  = (const float*)d_in[2];
  const float* w2  = (const float*)d_in[3];
  const float* b2  = (const float*)d_in[4];
  const float* w3  = (const float*)d_in[5];
  const float* b3  = (const float*)d_in[6];
  const float* fcw = (const float*)d_in[7];
  const float* fcb = (const float*)d_in[8];
  __bf16* wsb = (__bf16*)d_ws;
  float* out = (float*)d_out;

  hipLaunchKernelGGL(pack_weights, dim3(184), dim3(256), 0, stream, w1, w2, w3, wsb);
  hipLaunchKernelGGL(cnn_fused, dim3(2048), dim3(256), 0, stream,
                     x, wsb, b1, b2, b3, fcw, fcb, out);
}

// Round 14
// 157.893 us; speedup vs baseline: 1.1278x; 1.0314x over previous
//
#include <hip/hip_runtime.h>

typedef float f32x4 __attribute__((ext_vector_type(4)));
typedef float f32x16v __attribute__((ext_vector_type(16)));
typedef __bf16 bf16x4 __attribute__((ext_vector_type(4)));
typedef __bf16 bf16x8 __attribute__((ext_vector_type(8)));

union U4B8 { uint4 u; bf16x8 b; };

// ws layout (bf16 elements): b2p[9216] @0, b3p[36864] @9216, c1p[1024] @46080
#define B2P_OFF 0
#define B3P_OFF 9216
#define C1P_OFF 46080

// ------------------------------------------------------------- pack_weights
// b2p frag f=t*2+p: lane l, j: oc=l&31, ic=(l>>5)*8+j              (32x32x16)
// b3p frag f=t*8+nt*2+p: lane l, j: oc=nt*16+(l&15), ic=(l>>4)*8+j (16x16x32)
// c1p frag f in {Bh,Bl}: oc=l&15, k=(l>>4)*8+j, k = kx*9+ky*3+ic (<27), else 0
__global__ __launch_bounds__(256) void pack_weights(
    const float* __restrict__ w1, const float* __restrict__ w2,
    const float* __restrict__ w3, __bf16* __restrict__ wsb) {
  int i = blockIdx.x * 256 + threadIdx.x;
  if (i < 9216) {
    int f = i >> 9, r = i & 511;
    int l = r >> 3, j = r & 7;
    int t = f >> 1, p = f & 1;
    int ky = t / 3, kx = t % 3;
    int oc = l & 31, ic = ((l >> 5) << 3) + j;
    float v = w2[oc * 144 + ic * 9 + ky * 3 + kx];
    __bf16 hi = (__bf16)v;
    wsb[B2P_OFF + i] = p ? (__bf16)(v - (float)hi) : hi;
  } else if (i < 9216 + 36864) {
    int q = i - 9216;
    int f = q >> 9, r = q & 511;
    int l = r >> 3, j = r & 7;
    int t = f >> 3, nt = (f >> 1) & 3, p = f & 1;
    int ky = t / 3, kx = t % 3;
    int oc = nt * 16 + (l & 15), ic = ((l >> 4) << 3) + j;
    float v = w3[oc * 288 + ic * 9 + ky * 3 + kx];
    __bf16 hi = (__bf16)v;
    wsb[B3P_OFF + q] = p ? (__bf16)(v - (float)hi) : hi;
  } else if (i < 9216 + 36864 + 1024) {
    int q = i - (9216 + 36864);
    int f = q >> 9, r = q & 511;
    int l = r >> 3, j = r & 7;
    int oc = l & 15, k = ((l >> 4) << 3) + j;
    float v = 0.f;
    if (k < 27) {
      int kx = k / 9, rem = k % 9;
      int ky = rem / 3, ic = rem % 3;
      v = w1[oc * 27 + ic * 9 + ky * 3 + kx];
    }
    __bf16 hi = (__bf16)v;
    wsb[C1P_OFF + q] = f ? (__bf16)(v - (float)hi) : hi;
  }
}

// -------------------------------------------------------------- fused CNN
// R10 structure (best measured): 1 image/block, 4 waves, LDS 16128 B.
//   phase1: s_img @0 (9248B; cell = 4 ush [ic0,ic1,ic2,0])
//   phase2: s2 @0 (18 rows x 448 ush; cell 24 ush = 16 oc + pad, hi only)
//   phase3: s3 @0 (10 rows x 448 ush; cell 40 ush = 32 oc + pad, hi only)
//           h3s @8960 (4096B f32 [oc][py][px])
// NEW vs R10: bank-conflict swizzles on s2/s3 sub-cell slots:
//   s2: physical 16B-half = (oc>>3) ^ (col&1)   [reader: kh ^ (col&1)]
//   s3: physical 16B-quarter = ((oc>>3)+col)&3  [reader: (quad+col)&3]
// launch_bounds (256,4) -> 64-VGPR budget (empirical: ~512/(2*minwaves));
// R10 compiled spill-free at exactly 64 with this body.
__global__ __launch_bounds__(256, 4) void cnn_fused(
    const float* __restrict__ x, const __bf16* __restrict__ wsb,
    const float* __restrict__ b1, const float* __restrict__ b2,
    const float* __restrict__ b3,
    const float* __restrict__ fcw, const float* __restrict__ fcb,
    float* __restrict__ out) {
  __shared__ __align__(16) unsigned char smem[16128];
  __bf16* s_img = (__bf16*)smem;
  __bf16* s2b   = (__bf16*)smem;
  __bf16* s3b   = (__bf16*)smem;
  float*  h3s   = (float*)(smem + 8960);

  const __bf16* b2p = wsb + B2P_OFF;
  const __bf16* b3p = wsb + B3P_OFF;
  const __bf16* c1p = wsb + C1P_OFF;

  const int tid = threadIdx.x;
  const int img = blockIdx.x;
  const int w = tid >> 6, lane = tid & 63;

  // ---- phase 1: zero s_img halo (132 cells) + write interior (disjoint)
  if (tid < 132) {
    int row, col;
    if (tid < 34)       { row = 0;        col = tid; }
    else if (tid < 68)  { row = 33;       col = tid - 34; }
    else if (tid < 100) { row = tid - 67; col = 0; }
    else                { row = tid - 99; col = 33; }
    *(unsigned long long*)&s_img[(row * 34 + col) * 4] = 0ull;
  }
  const float* xg = x + img * 3072;
  for (int i = tid; i < 1024; i += 256) {
    const int y = i >> 5, xx = i & 31;
    bf16x4 pk;
    pk.x = (__bf16)xg[i];
    pk.y = (__bf16)xg[i + 1024];
    pk.z = (__bf16)xg[i + 2048];
    pk.w = (__bf16)0.f;
    *(bf16x4*)&s_img[((y + 1) * 34 + (xx + 1)) * 4] = pk;
  }
  const bf16x8 B1h = *(const bf16x8*)(c1p + lane * 8);
  const bf16x8 B1l = *(const bf16x8*)(c1p + 512 + lane * 8);
  __syncthreads();

  // ---- conv1: K=27-in-32 packed MFMA (R10-validated)
  float pooled[16];
  {
    const int xm = lane & 15, kg = lane >> 4;
    #pragma unroll
    for (int p = 0; p < 4; ++p) {
      f32x4 acc[2][2];
      #pragma unroll
      for (int ys = 0; ys < 2; ++ys)
        #pragma unroll
        for (int xh = 0; xh < 2; ++xh)
          #pragma unroll
          for (int r = 0; r < 4; ++r) acc[ys][xh][r] = 0.f;
      #pragma unroll
      for (int ys = 0; ys < 2; ++ys) {
        const int yqg = w * 8 + p * 2 + ys;
        #pragma unroll
        for (int xh = 0; xh < 2; ++xh) {
          const int xv = xh * 16 + xm;
          const int ca = xv + (kg <= 1 ? 0 : kg - 1);
          const int cb = xv + (kg < 2 ? 1 : 2);
          const uint2 qa0 = *(const uint2*)&s_img[((yqg + 0) * 34 + ca) * 4];
          const uint2 qa1 = *(const uint2*)&s_img[((yqg + 1) * 34 + ca) * 4];
          const uint2 qa2 = *(const uint2*)&s_img[((yqg + 2) * 34 + ca) * 4];
          const uint2 qb0 = *(const uint2*)&s_img[((yqg + 0) * 34 + cb) * 4];
          const uint2 qb1 = *(const uint2*)&s_img[((yqg + 1) * 34 + cb) * 4];
          const uint2 qb2 = *(const uint2*)&s_img[((yqg + 2) * 34 + cb) * 4];
          const uint a0 = qa0.x, a1 = qa0.y, a2 = qa1.x, a3 = qa1.y, a4 = qa2.x, a5 = qa2.y;
          const uint b0 = qb0.x, b1 = qb0.y, b2 = qb1.x, b3 = qb1.y, b4 = qb2.x;
          U4B8 A;
          A.u.x = kg == 0 ? a0
                : kg == 1 ? (a5 | (b0 << 16))
                : kg == 2 ? ((a4 >> 16) | (a5 << 16))
                :           a4;
          A.u.y = kg == 0 ? (a1 | (a2 << 16))
                : kg == 1 ? ((b0 >> 16) | (b1 << 16))
                : kg == 2 ? b0
                :           a5;
          A.u.z = kg == 0 ? ((a2 >> 16) | (a3 << 16))
                : kg == 1 ? b2
                : kg == 2 ? (b1 | (b2 << 16))
                :           0u;
          A.u.w = kg == 0 ? a4
                : kg == 1 ? (b3 | (b4 << 16))
                : kg == 2 ? ((b2 >> 16) | (b3 << 16))
                :           0u;
          acc[ys][xh] = __builtin_amdgcn_mfma_f32_16x16x32_bf16(A.b, B1h, acc[ys][xh], 0, 0, 0);
          acc[ys][xh] = __builtin_amdgcn_mfma_f32_16x16x32_bf16(A.b, B1l, acc[ys][xh], 0, 0, 0);
        }
      }
      #pragma unroll
      for (int xh = 0; xh < 2; ++xh)
        #pragma unroll
        for (int xp2 = 0; xp2 < 2; ++xp2) {
          const float v0 = fmaxf(acc[0][xh][xp2 * 2], acc[0][xh][xp2 * 2 + 1]);
          const float v1 = fmaxf(acc[1][xh][xp2 * 2], acc[1][xh][xp2 * 2 + 1]);
          pooled[p * 4 + xh * 2 + xp2] = fmaxf(v0, v1);
        }
    }
  }
  __syncthreads();   // s_img dead

  // ---- h1 (bias+relu, bf16 hi only) -> s2, half-swizzled
  if (tid < 68) {
    int row, col;
    if (tid < 18)      { row = 0;       col = tid; }
    else if (tid < 36) { row = 17;      col = tid - 18; }
    else if (tid < 52) { row = tid - 35; col = 0; }
    else               { row = tid - 51; col = 17; }
    unsigned long long* p = (unsigned long long*)&s2b[row * 448 + col * 24];
    p[0] = 0ull; p[1] = 0ull; p[2] = 0ull; p[3] = 0ull;
  }
  {
    const int oc = lane & 15, quad = lane >> 4;
    const float bias = b1[oc];
    #pragma unroll
    for (int p = 0; p < 4; ++p)
      #pragma unroll
      for (int xh = 0; xh < 2; ++xh)
        #pragma unroll
        for (int xp2 = 0; xp2 < 2; ++xp2) {
          const float v = fmaxf(pooled[p * 4 + xh * 2 + xp2] + bias, 0.f);
          const int py = w * 4 + p, px = xh * 8 + quad * 2 + xp2;
          const int col = px + 1;
          const int half = ((oc >> 3) ^ (col & 1)) << 3;   // swizzle
          s2b[(py + 1) * 448 + col * 24 + half + (oc & 7)] = (__bf16)v;
        }
  }
  bf16x8 Bf[18];
  #pragma unroll
  for (int f = 0; f < 18; ++f)
    Bf[f] = *(const bf16x8*)(b2p + f * 512 + lane * 8);
  __syncthreads();

  // ---- conv2 (2-term: a_h*(B_h+B_l)), swizzled reads
  float pooled2[8];
  {
    const unsigned short* s2 = (const unsigned short*)s2b;
    const int xm = lane & 15, yoff = (lane >> 4) & 1, kh = lane >> 5;
    f32x16v acc0, acc1;
    #pragma unroll
    for (int r = 0; r < 16; ++r) { acc0[r] = 0.f; acc1[r] = 0.f; }
    #pragma unroll
    for (int t = 0; t < 9; ++t) {
      const int ky = t / 3, kx = t % 3;
      const int C = xm + kx;
      const int col = C * 24 + ((kh ^ (C & 1)) << 3);      // swizzle
      const int row0 = (4 * w + yoff + ky) * 448 + col;
      const int row1 = row0 + 896;
      bf16x8 a0h = *(const bf16x8*)&s2[row0];
      bf16x8 a1h = *(const bf16x8*)&s2[row1];
      acc0 = __builtin_amdgcn_mfma_f32_32x32x16_bf16(a0h, Bf[t * 2],     acc0, 0, 0, 0);
      acc1 = __builtin_amdgcn_mfma_f32_32x32x16_bf16(a1h, Bf[t * 2],     acc1, 0, 0, 0);
      acc0 = __builtin_amdgcn_mfma_f32_32x32x16_bf16(a0h, Bf[t * 2 + 1], acc0, 0, 0, 0);
      acc1 = __builtin_amdgcn_mfma_f32_32x32x16_bf16(a1h, Bf[t * 2 + 1], acc1, 0, 0, 0);
    }
    #pragma unroll
    for (int i2 = 0; i2 < 2; ++i2) {
      const f32x16v& a = i2 ? acc1 : acc0;
      #pragma unroll
      for (int bq = 0; bq < 2; ++bq)
        #pragma unroll
        for (int rq = 0; rq < 2; ++rq) {
          const int r0 = bq * 4 + rq * 2;
          pooled2[i2 * 4 + bq * 2 + rq] =
              fmaxf(fmaxf(a[r0], a[r0 + 1]), fmaxf(a[r0 + 8], a[r0 + 9]));
        }
    }
  }
  __syncthreads();   // s2 dead

  // ---- h2 (bias+relu, bf16 hi only) -> s3, quarter-rotated
  if (tid < 36) {
    int row, col;
    if (tid < 10)      { row = 0;       col = tid; }
    else if (tid < 20) { row = 9;       col = tid - 10; }
    else if (tid < 28) { row = tid - 19; col = 0; }
    else               { row = tid - 27; col = 9; }
    unsigned long long* p = (unsigned long long*)&s3b[row * 448 + col * 40];
    #pragma unroll
    for (int u = 0; u < 8; ++u) p[u] = 0ull;
  }
  {
    const int oc = lane & 31, hh = lane >> 5;
    const float bias = b2[oc];
    #pragma unroll
    for (int i2 = 0; i2 < 2; ++i2)
      #pragma unroll
      for (int bq = 0; bq < 2; ++bq)
        #pragma unroll
        for (int rq = 0; rq < 2; ++rq) {
          const float v = fmaxf(pooled2[i2 * 4 + bq * 2 + rq] + bias, 0.f);
          const int py = 2 * w + i2, px = 2 * hh + 4 * bq + rq;
          const int col = px + 1;
          const int qr = (((oc >> 3) + col) & 3) << 3;     // rotate quarter
          s3b[(py + 1) * 448 + col * 40 + qr + (oc & 7)] = (__bf16)v;
        }
  }
  __syncthreads();

  // ---- conv3 (wave = nt = oc-tile), 2-term, rotated reads
  {
    const unsigned short* s3 = (const unsigned short*)s3b;
    const int nt = w;
    bf16x8 Bt[18];
    #pragma unroll
    for (int t = 0; t < 9; ++t) {
      Bt[t * 2]     = *(const bf16x8*)(b3p + (t * 8 + nt * 2) * 512 + lane * 8);
      Bt[t * 2 + 1] = *(const bf16x8*)(b3p + (t * 8 + nt * 2 + 1) * 512 + lane * 8);
    }
    const int m = lane & 15, quad = lane >> 4;
    const int xm = m & 7, yoff = m >> 3;
    f32x4 acc[4];
    #pragma unroll
    for (int mt = 0; mt < 4; ++mt)
      #pragma unroll
      for (int r = 0; r < 4; ++r) acc[mt][r] = 0.f;
    #pragma unroll
    for (int t = 0; t < 9; ++t) {
      const int ky = t / 3, kx = t % 3;
      const int C = xm + kx;
      const int coff = C * 40 + (((quad + C) & 3) << 3);   // rotate quarter
      #pragma unroll
      for (int mt = 0; mt < 4; ++mt) {
        const int ro = (2 * mt + yoff + ky) * 448 + coff;
        bf16x8 ah = *(const bf16x8*)&s3[ro];
        acc[mt] = __builtin_amdgcn_mfma_f32_16x16x32_bf16(ah, Bt[t * 2],     acc[mt], 0, 0, 0);
        acc[mt] = __builtin_amdgcn_mfma_f32_16x16x32_bf16(ah, Bt[t * 2 + 1], acc[mt], 0, 0, 0);
      }
    }
    // epilogue -> h3s (disjoint from s3's read region)
    const int ocl = lane & 15;
    #pragma unroll
    for (int mt = 0; mt < 4; ++mt) {
      float p0 = fmaxf(acc[mt][0], acc[mt][1]);
      float p1 = fmaxf(acc[mt][2], acc[mt][3]);
      p0 = fmaxf(p0, __shfl_xor(p0, 32, 64));
      p1 = fmaxf(p1, __shfl_xor(p1, 32, 64));
      if (quad < 2) {
        const int oc = nt * 16 + ocl;
        const float bias = b3[oc];
        const int base = oc * 16 + mt * 4 + (quad & 1) * 2;
        h3s[base]     = fmaxf(p0 + bias, 0.f);
        h3s[base + 1] = fmaxf(p1 + bias, 0.f);
      }
    }
  }
  __syncthreads();

  // ---- fc (wave 0)
  if (w == 0) {
    float hv[16];
    #pragma unroll
    for (int i = 0; i < 16; ++i) hv[i] = h3s[i * 64 + lane];
    #pragma unroll
    for (int j = 0; j < 10; ++j) {
      float dot = 0.f;
      #pragma unroll
      for (int i = 0; i < 16; ++i)
        dot = fmaf(hv[i], fcw[j * 1024 + i * 64 + lane], dot);
      #pragma unroll
      for (int s = 32; s > 0; s >>= 1) dot += __shfl_xor(dot, s, 64);
      if (lane == 0) out[img * 10 + j] = dot + fcb[j];
    }
  }
}

// -------------------------------------------------------------------- launch
extern "C" void kernel_launch(void* const* d_in, const int* in_sizes, int n_in,
                              void* d_out, int out_size, void* d_ws, size_t ws_size,
                              hipStream_t stream) {
  const float* x   = (const float*)d_in[0];
  const float* w1  = (const float*)d_in[1];
  const float* b1  = (const float*)d_in[2];
  const float* w2  = (const float*)d_in[3];
  const float* b2  = (const float*)d_in[4];
  const float* w3  = (const float*)d_in[5];
  const float* b3  = (const float*)d_in[6];
  const float* fcw = (const float*)d_in[7];
  const float* fcb = (const float*)d_in[8];
  __bf16* wsb = (__bf16*)d_ws;
  float* out = (float*)d_out;

  hipLaunchKernelGGL(pack_weights, dim3(184), dim3(256), 0, stream, w1, w2, w3, wsb);
  hipLaunchKernelGGL(cnn_fused, dim3(4096), dim3(256), 0, stream,
                     x, wsb, b1, b2, b3, fcw, fcb, out);
}

// Round 15
// 155.217 us; speedup vs baseline: 1.1472x; 1.0172x over previous
//
#include <hip/hip_runtime.h>

typedef float f32x4 __attribute__((ext_vector_type(4)));
typedef float f32x16v __attribute__((ext_vector_type(16)));
typedef __bf16 bf16x4 __attribute__((ext_vector_type(4)));
typedef __bf16 bf16x8 __attribute__((ext_vector_type(8)));

union U4B8 { uint4 u; bf16x8 b; };

// ws layout (bf16 elements): b2p[9216] @0, b3p[36864] @9216, c1p[1024] @46080
#define B2P_OFF 0
#define B3P_OFF 9216
#define C1P_OFF 46080

// ------------------------------------------------------------- pack_weights
// b2p frag f=t*2+p: lane l, j: oc=l&31, ic=(l>>5)*8+j              (32x32x16)
// b3p frag f=t*8+nt*2+p: lane l, j: oc=nt*16+(l&15), ic=(l>>4)*8+j (16x16x32)
// c1p frag f in {Bh,Bl}: oc=l&15, k=(l>>4)*8+j, k = kx*9+ky*3+ic (<27), else 0
__global__ __launch_bounds__(256) void pack_weights(
    const float* __restrict__ w1, const float* __restrict__ w2,
    const float* __restrict__ w3, __bf16* __restrict__ wsb) {
  int i = blockIdx.x * 256 + threadIdx.x;
  if (i < 9216) {
    int f = i >> 9, r = i & 511;
    int l = r >> 3, j = r & 7;
    int t = f >> 1, p = f & 1;
    int ky = t / 3, kx = t % 3;
    int oc = l & 31, ic = ((l >> 5) << 3) + j;
    float v = w2[oc * 144 + ic * 9 + ky * 3 + kx];
    __bf16 hi = (__bf16)v;
    wsb[B2P_OFF + i] = p ? (__bf16)(v - (float)hi) : hi;
  } else if (i < 9216 + 36864) {
    int q = i - 9216;
    int f = q >> 9, r = q & 511;
    int l = r >> 3, j = r & 7;
    int t = f >> 3, nt = (f >> 1) & 3, p = f & 1;
    int ky = t / 3, kx = t % 3;
    int oc = nt * 16 + (l & 15), ic = ((l >> 4) << 3) + j;
    float v = w3[oc * 288 + ic * 9 + ky * 3 + kx];
    __bf16 hi = (__bf16)v;
    wsb[B3P_OFF + q] = p ? (__bf16)(v - (float)hi) : hi;
  } else if (i < 9216 + 36864 + 1024) {
    int q = i - (9216 + 36864);
    int f = q >> 9, r = q & 511;
    int l = r >> 3, j = r & 7;
    int oc = l & 15, k = ((l >> 4) << 3) + j;
    float v = 0.f;
    if (k < 27) {
      int kx = k / 9, rem = k % 9;
      int ky = rem / 3, ic = rem % 3;
      v = w1[oc * 27 + ic * 9 + ky * 3 + kx];
    }
    __bf16 hi = (__bf16)v;
    wsb[C1P_OFF + q] = f ? (__bf16)(v - (float)hi) : hi;
  }
}

// -------------------------------------------------------------- fused CNN
// R10 structure (best measured: 82 us kernel). 1 image/block, 4 waves,
// LDS 16128 B. R14's swizzles REVERTED (they raised conflicts 4.1M->6.1M).
// NEW vs R10: conv1 is 1-term (w1-lo dropped; error contribution <=1e-3
// at output vs 0.034 threshold) -> conv1 MFMA count halved.
//   phase1: s_img @0 (9248B; cell = 4 ush [ic0,ic1,ic2,0])
//   phase2: s2 @0 (18 rows x 448 ush; cell 24 ush = 16 oc + pad, hi only)
//   phase3: s3 @0 (10 rows x 448 ush; cell 40 ush = 32 oc + pad, hi only)
//           h3s @8960 (4096B f32 [oc][py][px])
// launch_bounds (256,4) -> 64-VGPR budget (empirical: ~512/(2*minwaves));
// this body compiles spill-free at exactly 64 (R10).
__global__ __launch_bounds__(256, 4) void cnn_fused(
    const float* __restrict__ x, const __bf16* __restrict__ wsb,
    const float* __restrict__ b1, const float* __restrict__ b2,
    const float* __restrict__ b3,
    const float* __restrict__ fcw, const float* __restrict__ fcb,
    float* __restrict__ out) {
  __shared__ __align__(16) unsigned char smem[16128];
  __bf16* s_img = (__bf16*)smem;
  __bf16* s2b   = (__bf16*)smem;
  __bf16* s3b   = (__bf16*)smem;
  float*  h3s   = (float*)(smem + 8960);

  const __bf16* b2p = wsb + B2P_OFF;
  const __bf16* b3p = wsb + B3P_OFF;
  const __bf16* c1p = wsb + C1P_OFF;

  const int tid = threadIdx.x;
  const int img = blockIdx.x;
  const int w = tid >> 6, lane = tid & 63;

  // ---- phase 1: zero s_img halo (132 cells) + write interior (disjoint)
  if (tid < 132) {
    int row, col;
    if (tid < 34)       { row = 0;        col = tid; }
    else if (tid < 68)  { row = 33;       col = tid - 34; }
    else if (tid < 100) { row = tid - 67; col = 0; }
    else                { row = tid - 99; col = 33; }
    *(unsigned long long*)&s_img[(row * 34 + col) * 4] = 0ull;
  }
  const float* xg = x + img * 3072;
  for (int i = tid; i < 1024; i += 256) {
    const int y = i >> 5, xx = i & 31;
    bf16x4 pk;
    pk.x = (__bf16)xg[i];
    pk.y = (__bf16)xg[i + 1024];
    pk.z = (__bf16)xg[i + 2048];
    pk.w = (__bf16)0.f;
    *(bf16x4*)&s_img[((y + 1) * 34 + (xx + 1)) * 4] = pk;
  }
  const bf16x8 B1h = *(const bf16x8*)(c1p + lane * 8);
  __syncthreads();

  // ---- conv1: K=27-in-32 packed MFMA, 1-term (B1h only)
  float pooled[16];
  {
    const int xm = lane & 15, kg = lane >> 4;
    #pragma unroll
    for (int p = 0; p < 4; ++p) {
      f32x4 acc[2][2];
      #pragma unroll
      for (int ys = 0; ys < 2; ++ys)
        #pragma unroll
        for (int xh = 0; xh < 2; ++xh)
          #pragma unroll
          for (int r = 0; r < 4; ++r) acc[ys][xh][r] = 0.f;
      #pragma unroll
      for (int ys = 0; ys < 2; ++ys) {
        const int yqg = w * 8 + p * 2 + ys;
        #pragma unroll
        for (int xh = 0; xh < 2; ++xh) {
          const int xv = xh * 16 + xm;
          const int ca = xv + (kg <= 1 ? 0 : kg - 1);
          const int cb = xv + (kg < 2 ? 1 : 2);
          const uint2 qa0 = *(const uint2*)&s_img[((yqg + 0) * 34 + ca) * 4];
          const uint2 qa1 = *(const uint2*)&s_img[((yqg + 1) * 34 + ca) * 4];
          const uint2 qa2 = *(const uint2*)&s_img[((yqg + 2) * 34 + ca) * 4];
          const uint2 qb0 = *(const uint2*)&s_img[((yqg + 0) * 34 + cb) * 4];
          const uint2 qb1 = *(const uint2*)&s_img[((yqg + 1) * 34 + cb) * 4];
          const uint2 qb2 = *(const uint2*)&s_img[((yqg + 2) * 34 + cb) * 4];
          const uint a0 = qa0.x, a1 = qa0.y, a2 = qa1.x, a3 = qa1.y, a4 = qa2.x, a5 = qa2.y;
          const uint b0 = qb0.x, b1 = qb0.y, b2 = qb1.x, b3 = qb1.y, b4 = qb2.x;
          U4B8 A;
          A.u.x = kg == 0 ? a0
                : kg == 1 ? (a5 | (b0 << 16))
                : kg == 2 ? ((a4 >> 16) | (a5 << 16))
                :           a4;
          A.u.y = kg == 0 ? (a1 | (a2 << 16))
                : kg == 1 ? ((b0 >> 16) | (b1 << 16))
                : kg == 2 ? b0
                :           a5;
          A.u.z = kg == 0 ? ((a2 >> 16) | (a3 << 16))
                : kg == 1 ? b2
                : kg == 2 ? (b1 | (b2 << 16))
                :           0u;
          A.u.w = kg == 0 ? a4
                : kg == 1 ? (b3 | (b4 << 16))
                : kg == 2 ? ((b2 >> 16) | (b3 << 16))
                :           0u;
          acc[ys][xh] = __builtin_amdgcn_mfma_f32_16x16x32_bf16(A.b, B1h, acc[ys][xh], 0, 0, 0);
        }
      }
      #pragma unroll
      for (int xh = 0; xh < 2; ++xh)
        #pragma unroll
        for (int xp2 = 0; xp2 < 2; ++xp2) {
          const float v0 = fmaxf(acc[0][xh][xp2 * 2], acc[0][xh][xp2 * 2 + 1]);
          const float v1 = fmaxf(acc[1][xh][xp2 * 2], acc[1][xh][xp2 * 2 + 1]);
          pooled[p * 4 + xh * 2 + xp2] = fmaxf(v0, v1);
        }
    }
  }
  __syncthreads();   // s_img dead

  // ---- h1 (bias+relu, bf16 hi only) -> s2 (row stride 448, cell 24)
  if (tid < 68) {
    int row, col;
    if (tid < 18)      { row = 0;       col = tid; }
    else if (tid < 36) { row = 17;      col = tid - 18; }
    else if (tid < 52) { row = tid - 35; col = 0; }
    else               { row = tid - 51; col = 17; }
    unsigned long long* p = (unsigned long long*)&s2b[row * 448 + col * 24];
    p[0] = 0ull; p[1] = 0ull; p[2] = 0ull; p[3] = 0ull;
  }
  {
    const int oc = lane & 15, quad = lane >> 4;
    const float bias = b1[oc];
    #pragma unroll
    for (int p = 0; p < 4; ++p)
      #pragma unroll
      for (int xh = 0; xh < 2; ++xh)
        #pragma unroll
        for (int xp2 = 0; xp2 < 2; ++xp2) {
          const float v = fmaxf(pooled[p * 4 + xh * 2 + xp2] + bias, 0.f);
          const int py = w * 4 + p, px = xh * 8 + quad * 2 + xp2;
          s2b[(py + 1) * 448 + (px + 1) * 24 + oc] = (__bf16)v;
        }
  }
  bf16x8 Bf[18];
  #pragma unroll
  for (int f = 0; f < 18; ++f)
    Bf[f] = *(const bf16x8*)(b2p + f * 512 + lane * 8);
  __syncthreads();

  // ---- conv2 (2-term: a_h*(B_h+B_l)), stride-448 addressing
  float pooled2[8];
  {
    const unsigned short* s2 = (const unsigned short*)s2b;
    const int xm = lane & 15, yoff = (lane >> 4) & 1, kh = lane >> 5;
    f32x16v acc0, acc1;
    #pragma unroll
    for (int r = 0; r < 16; ++r) { acc0[r] = 0.f; acc1[r] = 0.f; }
    #pragma unroll
    for (int t = 0; t < 9; ++t) {
      const int ky = t / 3, kx = t % 3;
      const int col = (xm + kx) * 24 + kh * 8;
      const int row0 = (4 * w + yoff + ky) * 448 + col;
      const int row1 = row0 + 896;
      bf16x8 a0h = *(const bf16x8*)&s2[row0];
      bf16x8 a1h = *(const bf16x8*)&s2[row1];
      acc0 = __builtin_amdgcn_mfma_f32_32x32x16_bf16(a0h, Bf[t * 2],     acc0, 0, 0, 0);
      acc1 = __builtin_amdgcn_mfma_f32_32x32x16_bf16(a1h, Bf[t * 2],     acc1, 0, 0, 0);
      acc0 = __builtin_amdgcn_mfma_f32_32x32x16_bf16(a0h, Bf[t * 2 + 1], acc0, 0, 0, 0);
      acc1 = __builtin_amdgcn_mfma_f32_32x32x16_bf16(a1h, Bf[t * 2 + 1], acc1, 0, 0, 0);
    }
    #pragma unroll
    for (int i2 = 0; i2 < 2; ++i2) {
      const f32x16v& a = i2 ? acc1 : acc0;
      #pragma unroll
      for (int bq = 0; bq < 2; ++bq)
        #pragma unroll
        for (int rq = 0; rq < 2; ++rq) {
          const int r0 = bq * 4 + rq * 2;
          pooled2[i2 * 4 + bq * 2 + rq] =
              fmaxf(fmaxf(a[r0], a[r0 + 1]), fmaxf(a[r0 + 8], a[r0 + 9]));
        }
    }
  }
  __syncthreads();   // s2 dead

  // ---- h2 (bias+relu, bf16 hi only) -> s3 (row stride 448, cell 40)
  if (tid < 36) {
    int row, col;
    if (tid < 10)      { row = 0;       col = tid; }
    else if (tid < 20) { row = 9;       col = tid - 10; }
    else if (tid < 28) { row = tid - 19; col = 0; }
    else               { row = tid - 27; col = 9; }
    unsigned long long* p = (unsigned long long*)&s3b[row * 448 + col * 40];
    #pragma unroll
    for (int u = 0; u < 8; ++u) p[u] = 0ull;
  }
  {
    const int oc = lane & 31, hh = lane >> 5;
    const float bias = b2[oc];
    #pragma unroll
    for (int i2 = 0; i2 < 2; ++i2)
      #pragma unroll
      for (int bq = 0; bq < 2; ++bq)
        #pragma unroll
        for (int rq = 0; rq < 2; ++rq) {
          const float v = fmaxf(pooled2[i2 * 4 + bq * 2 + rq] + bias, 0.f);
          const int py = 2 * w + i2, px = 2 * hh + 4 * bq + rq;
          s3b[(py + 1) * 448 + (px + 1) * 40 + oc] = (__bf16)v;
        }
  }
  __syncthreads();

  // ---- conv3 (wave = nt = oc-tile), 2-term
  {
    const unsigned short* s3 = (const unsigned short*)s3b;
    const int nt = w;
    bf16x8 Bt[18];
    #pragma unroll
    for (int t = 0; t < 9; ++t) {
      Bt[t * 2]     = *(const bf16x8*)(b3p + (t * 8 + nt * 2) * 512 + lane * 8);
      Bt[t * 2 + 1] = *(const bf16x8*)(b3p + (t * 8 + nt * 2 + 1) * 512 + lane * 8);
    }
    const int m = lane & 15, quad = lane >> 4;
    const int xm = m & 7, yoff = m >> 3;
    f32x4 acc[4];
    #pragma unroll
    for (int mt = 0; mt < 4; ++mt)
      #pragma unroll
      for (int r = 0; r < 4; ++r) acc[mt][r] = 0.f;
    #pragma unroll
    for (int t = 0; t < 9; ++t) {
      const int ky = t / 3, kx = t % 3;
      #pragma unroll
      for (int mt = 0; mt < 4; ++mt) {
        const int ro = (2 * mt + yoff + ky) * 448 + (xm + kx) * 40 + quad * 8;
        bf16x8 ah = *(const bf16x8*)&s3[ro];
        acc[mt] = __builtin_amdgcn_mfma_f32_16x16x32_bf16(ah, Bt[t * 2],     acc[mt], 0, 0, 0);
        acc[mt] = __builtin_amdgcn_mfma_f32_16x16x32_bf16(ah, Bt[t * 2 + 1], acc[mt], 0, 0, 0);
      }
    }
    // epilogue -> h3s (disjoint from s3's read region)
    const int ocl = lane & 15;
    #pragma unroll
    for (int mt = 0; mt < 4; ++mt) {
      float p0 = fmaxf(acc[mt][0], acc[mt][1]);
      float p1 = fmaxf(acc[mt][2], acc[mt][3]);
      p0 = fmaxf(p0, __shfl_xor(p0, 32, 64));
      p1 = fmaxf(p1, __shfl_xor(p1, 32, 64));
      if (quad < 2) {
        const int oc = nt * 16 + ocl;
        const float bias = b3[oc];
        const int base = oc * 16 + mt * 4 + (quad & 1) * 2;
        h3s[base]     = fmaxf(p0 + bias, 0.f);
        h3s[base + 1] = fmaxf(p1 + bias, 0.f);
      }
    }
  }
  __syncthreads();

  // ---- fc (wave 0)
  if (w == 0) {
    float hv[16];
    #pragma unroll
    for (int i = 0; i < 16; ++i) hv[i] = h3s[i * 64 + lane];
    #pragma unroll
    for (int j = 0; j < 10; ++j) {
      float dot = 0.f;
      #pragma unroll
      for (int i = 0; i < 16; ++i)
        dot = fmaf(hv[i], fcw[j * 1024 + i * 64 + lane], dot);
      #pragma unroll
      for (int s = 32; s > 0; s >>= 1) dot += __shfl_xor(dot, s, 64);
      if (lane == 0) out[img * 10 + j] = dot + fcb[j];
    }
  }
}

// -------------------------------------------------------------------- launch
extern "C" void kernel_launch(void* const* d_in, const int* in_sizes, int n_in,
                              void* d_out, int out_size, void* d_ws, size_t ws_size,
                              hipStream_t stream) {
  const float* x   = (const float*)d_in[0];
  const float* w1  = (const float*)d_in[1];
  const float* b1  = (const float*)d_in[2];
  const float* w2  = (const float*)d_in[3];
  const float* b2  = (const float*)d_in[4];
  const float* w3  = (const float*)d_in[5];
  const float* b3  = (const float*)d_in[6];
  const float* fcw = (const float*)d_in[7];
  const float* fcb = (const float*)d_in[8];
  __bf16* wsb = (__bf16*)d_ws;
  float* out = (float*)d_out;

  hipLaunchKernelGGL(pack_weights, dim3(184), dim3(256), 0, stream, w1, w2, w3, wsb);
  hipLaunchKernelGGL(cnn_fused, dim3(4096), dim3(256), 0, stream,
                     x, wsb, b1, b2, b3, fcw, fcb, out);
}

// Round 16
// 153.255 us; speedup vs baseline: 1.1619x; 1.0128x over previous
//
#include <hip/hip_runtime.h>

typedef float f32x4 __attribute__((ext_vector_type(4)));
typedef float f32x16v __attribute__((ext_vector_type(16)));
typedef __bf16 bf16x4 __attribute__((ext_vector_type(4)));
typedef __bf16 bf16x8 __attribute__((ext_vector_type(8)));

union U4B8 { uint4 u; bf16x8 b; };

// ws layout (bf16 elements): b2p[9216] @0, b3p[36864] @9216, c1p[1024] @46080
#define B2P_OFF 0
#define B3P_OFF 9216
#define C1P_OFF 46080

// ------------------------------------------------------------- pack_weights
// b2p frag f=t*2+p: lane l, j: oc=l&31, ic=(l>>5)*8+j              (32x32x16)
// b3p frag f=t*8+nt*2+p: lane l, j: oc=nt*16+(l&15), ic=(l>>4)*8+j (16x16x32)
// c1p frag f in {Bh,Bl}: oc=l&15, k=(l>>4)*8+j, k = kx*9+ky*3+ic (<27), else 0
__global__ __launch_bounds__(256) void pack_weights(
    const float* __restrict__ w1, const float* __restrict__ w2,
    const float* __restrict__ w3, __bf16* __restrict__ wsb) {
  int i = blockIdx.x * 256 + threadIdx.x;
  if (i < 9216) {
    int f = i >> 9, r = i & 511;
    int l = r >> 3, j = r & 7;
    int t = f >> 1, p = f & 1;
    int ky = t / 3, kx = t % 3;
    int oc = l & 31, ic = ((l >> 5) << 3) + j;
    float v = w2[oc * 144 + ic * 9 + ky * 3 + kx];
    __bf16 hi = (__bf16)v;
    wsb[B2P_OFF + i] = p ? (__bf16)(v - (float)hi) : hi;
  } else if (i < 9216 + 36864) {
    int q = i - 9216;
    int f = q >> 9, r = q & 511;
    int l = r >> 3, j = r & 7;
    int t = f >> 3, nt = (f >> 1) & 3, p = f & 1;
    int ky = t / 3, kx = t % 3;
    int oc = nt * 16 + (l & 15), ic = ((l >> 4) << 3) + j;
    float v = w3[oc * 288 + ic * 9 + ky * 3 + kx];
    __bf16 hi = (__bf16)v;
    wsb[B3P_OFF + q] = p ? (__bf16)(v - (float)hi) : hi;
  } else if (i < 9216 + 36864 + 1024) {
    int q = i - (9216 + 36864);
    int f = q >> 9, r = q & 511;
    int l = r >> 3, j = r & 7;
    int oc = l & 15, k = ((l >> 4) << 3) + j;
    float v = 0.f;
    if (k < 27) {
      int kx = k / 9, rem = k % 9;
      int ky = rem / 3, ic = rem % 3;
      v = w1[oc * 27 + ic * 9 + ky * 3 + kx];
    }
    __bf16 hi = (__bf16)v;
    wsb[C1P_OFF + q] = f ? (__bf16)(v - (float)hi) : hi;
  }
}

// -------------------------------------------------------------- fused CNN
// R15 structure (best: 80 us kernel). 1 image/block, 4 waves, LDS 16128 B.
// NEW vs R15: (a) conv2 computes its two independent y-halves sequentially
// reusing ONE f32x16 accumulator — halves peak AGPR (32->16) under the
// gfx950 unified VGPR/AGPR file (suspected occupancy limiter);
// (b) fc spread across all 4 waves (j = w, w+4, ...).
//   phase1: s_img @0 (9248B; cell = 4 ush [ic0,ic1,ic2,0])
//   phase2: s2 @0 (18 rows x 448 ush; cell 24 ush = 16 oc + pad, hi only)
//   phase3: s3 @0 (10 rows x 448 ush; cell 40 ush = 32 oc + pad, hi only)
//           h3s @8960 (4096B f32 [oc][py][px])
// launch_bounds (256,4) -> 64-VGPR budget (empirical: ~512/(2*minwaves)).
__global__ __launch_bounds__(256, 4) void cnn_fused(
    const float* __restrict__ x, const __bf16* __restrict__ wsb,
    const float* __restrict__ b1, const float* __restrict__ b2,
    const float* __restrict__ b3,
    const float* __restrict__ fcw, const float* __restrict__ fcb,
    float* __restrict__ out) {
  __shared__ __align__(16) unsigned char smem[16128];
  __bf16* s_img = (__bf16*)smem;
  __bf16* s2b   = (__bf16*)smem;
  __bf16* s3b   = (__bf16*)smem;
  float*  h3s   = (float*)(smem + 8960);

  const __bf16* b2p = wsb + B2P_OFF;
  const __bf16* b3p = wsb + B3P_OFF;
  const __bf16* c1p = wsb + C1P_OFF;

  const int tid = threadIdx.x;
  const int img = blockIdx.x;
  const int w = tid >> 6, lane = tid & 63;

  // ---- phase 1: zero s_img halo (132 cells) + write interior (disjoint)
  if (tid < 132) {
    int row, col;
    if (tid < 34)       { row = 0;        col = tid; }
    else if (tid < 68)  { row = 33;       col = tid - 34; }
    else if (tid < 100) { row = tid - 67; col = 0; }
    else                { row = tid - 99; col = 33; }
    *(unsigned long long*)&s_img[(row * 34 + col) * 4] = 0ull;
  }
  const float* xg = x + img * 3072;
  for (int i = tid; i < 1024; i += 256) {
    const int y = i >> 5, xx = i & 31;
    bf16x4 pk;
    pk.x = (__bf16)xg[i];
    pk.y = (__bf16)xg[i + 1024];
    pk.z = (__bf16)xg[i + 2048];
    pk.w = (__bf16)0.f;
    *(bf16x4*)&s_img[((y + 1) * 34 + (xx + 1)) * 4] = pk;
  }
  const bf16x8 B1h = *(const bf16x8*)(c1p + lane * 8);
  __syncthreads();

  // ---- conv1: K=27-in-32 packed MFMA, 1-term (R15-validated)
  float pooled[16];
  {
    const int xm = lane & 15, kg = lane >> 4;
    #pragma unroll
    for (int p = 0; p < 4; ++p) {
      f32x4 acc[2][2];
      #pragma unroll
      for (int ys = 0; ys < 2; ++ys)
        #pragma unroll
        for (int xh = 0; xh < 2; ++xh)
          #pragma unroll
          for (int r = 0; r < 4; ++r) acc[ys][xh][r] = 0.f;
      #pragma unroll
      for (int ys = 0; ys < 2; ++ys) {
        const int yqg = w * 8 + p * 2 + ys;
        #pragma unroll
        for (int xh = 0; xh < 2; ++xh) {
          const int xv = xh * 16 + xm;
          const int ca = xv + (kg <= 1 ? 0 : kg - 1);
          const int cb = xv + (kg < 2 ? 1 : 2);
          const uint2 qa0 = *(const uint2*)&s_img[((yqg + 0) * 34 + ca) * 4];
          const uint2 qa1 = *(const uint2*)&s_img[((yqg + 1) * 34 + ca) * 4];
          const uint2 qa2 = *(const uint2*)&s_img[((yqg + 2) * 34 + ca) * 4];
          const uint2 qb0 = *(const uint2*)&s_img[((yqg + 0) * 34 + cb) * 4];
          const uint2 qb1 = *(const uint2*)&s_img[((yqg + 1) * 34 + cb) * 4];
          const uint2 qb2 = *(const uint2*)&s_img[((yqg + 2) * 34 + cb) * 4];
          const uint a0 = qa0.x, a1 = qa0.y, a2 = qa1.x, a3 = qa1.y, a4 = qa2.x, a5 = qa2.y;
          const uint b0 = qb0.x, b1 = qb0.y, b2 = qb1.x, b3 = qb1.y, b4 = qb2.x;
          U4B8 A;
          A.u.x = kg == 0 ? a0
                : kg == 1 ? (a5 | (b0 << 16))
                : kg == 2 ? ((a4 >> 16) | (a5 << 16))
                :           a4;
          A.u.y = kg == 0 ? (a1 | (a2 << 16))
                : kg == 1 ? ((b0 >> 16) | (b1 << 16))
                : kg == 2 ? b0
                :           a5;
          A.u.z = kg == 0 ? ((a2 >> 16) | (a3 << 16))
                : kg == 1 ? b2
                : kg == 2 ? (b1 | (b2 << 16))
                :           0u;
          A.u.w = kg == 0 ? a4
                : kg == 1 ? (b3 | (b4 << 16))
                : kg == 2 ? ((b2 >> 16) | (b3 << 16))
                :           0u;
          acc[ys][xh] = __builtin_amdgcn_mfma_f32_16x16x32_bf16(A.b, B1h, acc[ys][xh], 0, 0, 0);
        }
      }
      #pragma unroll
      for (int xh = 0; xh < 2; ++xh)
        #pragma unroll
        for (int xp2 = 0; xp2 < 2; ++xp2) {
          const float v0 = fmaxf(acc[0][xh][xp2 * 2], acc[0][xh][xp2 * 2 + 1]);
          const float v1 = fmaxf(acc[1][xh][xp2 * 2], acc[1][xh][xp2 * 2 + 1]);
          pooled[p * 4 + xh * 2 + xp2] = fmaxf(v0, v1);
        }
    }
  }
  __syncthreads();   // s_img dead

  // ---- h1 (bias+relu, bf16 hi only) -> s2 (row stride 448, cell 24)
  if (tid < 68) {
    int row, col;
    if (tid < 18)      { row = 0;       col = tid; }
    else if (tid < 36) { row = 17;      col = tid - 18; }
    else if (tid < 52) { row = tid - 35; col = 0; }
    else               { row = tid - 51; col = 17; }
    unsigned long long* p = (unsigned long long*)&s2b[row * 448 + col * 24];
    p[0] = 0ull; p[1] = 0ull; p[2] = 0ull; p[3] = 0ull;
  }
  {
    const int oc = lane & 15, quad = lane >> 4;
    const float bias = b1[oc];
    #pragma unroll
    for (int p = 0; p < 4; ++p)
      #pragma unroll
      for (int xh = 0; xh < 2; ++xh)
        #pragma unroll
        for (int xp2 = 0; xp2 < 2; ++xp2) {
          const float v = fmaxf(pooled[p * 4 + xh * 2 + xp2] + bias, 0.f);
          const int py = w * 4 + p, px = xh * 8 + quad * 2 + xp2;
          s2b[(py + 1) * 448 + (px + 1) * 24 + oc] = (__bf16)v;
        }
  }
  bf16x8 Bf[18];
  #pragma unroll
  for (int f = 0; f < 18; ++f)
    Bf[f] = *(const bf16x8*)(b2p + f * 512 + lane * 8);
  __syncthreads();

  // ---- conv2 (2-term), y-halves SEQUENTIAL (one f32x16 acc alive)
  float pooled2[8];
  {
    const unsigned short* s2 = (const unsigned short*)s2b;
    const int xm = lane & 15, yoff = (lane >> 4) & 1, kh = lane >> 5;
    #pragma unroll
    for (int i2 = 0; i2 < 2; ++i2) {
      f32x16v acc;
      #pragma unroll
      for (int r = 0; r < 16; ++r) acc[r] = 0.f;
      const int rbase = (4 * w + yoff + 2 * i2) * 448;
      #pragma unroll
      for (int t = 0; t < 9; ++t) {
        const int ky = t / 3, kx = t % 3;
        const int ro = rbase + ky * 448 + (xm + kx) * 24 + kh * 8;
        bf16x8 ah = *(const bf16x8*)&s2[ro];
        acc = __builtin_amdgcn_mfma_f32_32x32x16_bf16(ah, Bf[t * 2],     acc, 0, 0, 0);
        acc = __builtin_amdgcn_mfma_f32_32x32x16_bf16(ah, Bf[t * 2 + 1], acc, 0, 0, 0);
      }
      #pragma unroll
      for (int bq = 0; bq < 2; ++bq)
        #pragma unroll
        for (int rq = 0; rq < 2; ++rq) {
          const int r0 = bq * 4 + rq * 2;
          pooled2[i2 * 4 + bq * 2 + rq] =
              fmaxf(fmaxf(acc[r0], acc[r0 + 1]), fmaxf(acc[r0 + 8], acc[r0 + 9]));
        }
    }
  }
  __syncthreads();   // s2 dead

  // ---- h2 (bias+relu, bf16 hi only) -> s3 (row stride 448, cell 40)
  if (tid < 36) {
    int row, col;
    if (tid < 10)      { row = 0;       col = tid; }
    else if (tid < 20) { row = 9;       col = tid - 10; }
    else if (tid < 28) { row = tid - 19; col = 0; }
    else               { row = tid - 27; col = 9; }
    unsigned long long* p = (unsigned long long*)&s3b[row * 448 + col * 40];
    #pragma unroll
    for (int u = 0; u < 8; ++u) p[u] = 0ull;
  }
  {
    const int oc = lane & 31, hh = lane >> 5;
    const float bias = b2[oc];
    #pragma unroll
    for (int i2 = 0; i2 < 2; ++i2)
      #pragma unroll
      for (int bq = 0; bq < 2; ++bq)
        #pragma unroll
        for (int rq = 0; rq < 2; ++rq) {
          const float v = fmaxf(pooled2[i2 * 4 + bq * 2 + rq] + bias, 0.f);
          const int py = 2 * w + i2, px = 2 * hh + 4 * bq + rq;
          s3b[(py + 1) * 448 + (px + 1) * 40 + oc] = (__bf16)v;
        }
  }
  __syncthreads();

  // ---- conv3 (wave = nt = oc-tile), 2-term
  {
    const unsigned short* s3 = (const unsigned short*)s3b;
    const int nt = w;
    bf16x8 Bt[18];
    #pragma unroll
    for (int t = 0; t < 9; ++t) {
      Bt[t * 2]     = *(const bf16x8*)(b3p + (t * 8 + nt * 2) * 512 + lane * 8);
      Bt[t * 2 + 1] = *(const bf16x8*)(b3p + (t * 8 + nt * 2 + 1) * 512 + lane * 8);
    }
    const int m = lane & 15, quad = lane >> 4;
    const int xm = m & 7, yoff = m >> 3;
    f32x4 acc[4];
    #pragma unroll
    for (int mt = 0; mt < 4; ++mt)
      #pragma unroll
      for (int r = 0; r < 4; ++r) acc[mt][r] = 0.f;
    #pragma unroll
    for (int t = 0; t < 9; ++t) {
      const int ky = t / 3, kx = t % 3;
      #pragma unroll
      for (int mt = 0; mt < 4; ++mt) {
        const int ro = (2 * mt + yoff + ky) * 448 + (xm + kx) * 40 + quad * 8;
        bf16x8 ah = *(const bf16x8*)&s3[ro];
        acc[mt] = __builtin_amdgcn_mfma_f32_16x16x32_bf16(ah, Bt[t * 2],     acc[mt], 0, 0, 0);
        acc[mt] = __builtin_amdgcn_mfma_f32_16x16x32_bf16(ah, Bt[t * 2 + 1], acc[mt], 0, 0, 0);
      }
    }
    // epilogue -> h3s (disjoint from s3's read region)
    const int ocl = lane & 15;
    #pragma unroll
    for (int mt = 0; mt < 4; ++mt) {
      float p0 = fmaxf(acc[mt][0], acc[mt][1]);
      float p1 = fmaxf(acc[mt][2], acc[mt][3]);
      p0 = fmaxf(p0, __shfl_xor(p0, 32, 64));
      p1 = fmaxf(p1, __shfl_xor(p1, 32, 64));
      if (quad < 2) {
        const int oc = nt * 16 + ocl;
        const float bias = b3[oc];
        const int base = oc * 16 + mt * 4 + (quad & 1) * 2;
        h3s[base]     = fmaxf(p0 + bias, 0.f);
        h3s[base + 1] = fmaxf(p1 + bias, 0.f);
      }
    }
  }
  __syncthreads();

  // ---- fc: all 4 waves, wave w handles outputs j = w, w+4, ...
  {
    float hv[16];
    #pragma unroll
    for (int i = 0; i < 16; ++i) hv[i] = h3s[i * 64 + lane];
    for (int j = w; j < 10; j += 4) {
      float dot = 0.f;
      #pragma unroll
      for (int i = 0; i < 16; ++i)
        dot = fmaf(hv[i], fcw[j * 1024 + i * 64 + lane], dot);
      #pragma unroll
      for (int s = 32; s > 0; s >>= 1) dot += __shfl_xor(dot, s, 64);
      if (lane == 0) out[img * 10 + j] = dot + fcb[j];
    }
  }
}

// -------------------------------------------------------------------- launch
extern "C" void kernel_launch(void* const* d_in, const int* in_sizes, int n_in,
                              void* d_out, int out_size, void* d_ws, size_t ws_size,
                              hipStream_t stream) {
  const float* x   = (const float*)d_in[0];
  const float* w1  = (const float*)d_in[1];
  const float* b1  = (const float*)d_in[2];
  const float* w2  = (const float*)d_in[3];
  const float* b2  = (const float*)d_in[4];
  const float* w3  = (const float*)d_in[5];
  const float* b3  = (const float*)d_in[6];
  const float* fcw = (const float*)d_in[7];
  const float* fcb = (const float*)d_in[8];
  __bf16* wsb = (__bf16*)d_ws;
  float* out = (float*)d_out;

  hipLaunchKernelGGL(pack_weights, dim3(184), dim3(256), 0, stream, w1, w2, w3, wsb);
  hipLaunchKernelGGL(cnn_fused, dim3(4096), dim3(256), 0, stream,
                     x, wsb, b1, b2, b3, fcw, fcb, out);
}

// Round 17
// 152.484 us; speedup vs baseline: 1.1678x; 1.0051x over previous
//
#include <hip/hip_runtime.h>

typedef float f32x4 __attribute__((ext_vector_type(4)));
typedef float f32x16v __attribute__((ext_vector_type(16)));
typedef __bf16 bf16x4 __attribute__((ext_vector_type(4)));
typedef __bf16 bf16x8 __attribute__((ext_vector_type(8)));

union U4B8 { uint4 u; bf16x8 b; };

// ws layout (bf16 elements): b2p[9216] @0, b3p[36864] @9216, c1p[1024] @46080
#define B2P_OFF 0
#define B3P_OFF 9216
#define C1P_OFF 46080

// ------------------------------------------------------------- pack_weights
// b2p frag f=t*2+p: lane l, j: oc=l&31, ic=(l>>5)*8+j              (32x32x16)
// b3p frag f=t*8+nt*2+p: lane l, j: oc=nt*16+(l&15), ic=(l>>4)*8+j (16x16x32)
// c1p frag f in {Bh,Bl}: oc=l&15, k=(l>>4)*8+j, k = kx*9+ky*3+ic (<27), else 0
__global__ __launch_bounds__(256) void pack_weights(
    const float* __restrict__ w1, const float* __restrict__ w2,
    const float* __restrict__ w3, __bf16* __restrict__ wsb) {
  int i = blockIdx.x * 256 + threadIdx.x;
  if (i < 9216) {
    int f = i >> 9, r = i & 511;
    int l = r >> 3, j = r & 7;
    int t = f >> 1, p = f & 1;
    int ky = t / 3, kx = t % 3;
    int oc = l & 31, ic = ((l >> 5) << 3) + j;
    float v = w2[oc * 144 + ic * 9 + ky * 3 + kx];
    __bf16 hi = (__bf16)v;
    wsb[B2P_OFF + i] = p ? (__bf16)(v - (float)hi) : hi;
  } else if (i < 9216 + 36864) {
    int q = i - 9216;
    int f = q >> 9, r = q & 511;
    int l = r >> 3, j = r & 7;
    int t = f >> 3, nt = (f >> 1) & 3, p = f & 1;
    int ky = t / 3, kx = t % 3;
    int oc = nt * 16 + (l & 15), ic = ((l >> 4) << 3) + j;
    float v = w3[oc * 288 + ic * 9 + ky * 3 + kx];
    __bf16 hi = (__bf16)v;
    wsb[B3P_OFF + q] = p ? (__bf16)(v - (float)hi) : hi;
  } else if (i < 9216 + 36864 + 1024) {
    int q = i - (9216 + 36864);
    int f = q >> 9, r = q & 511;
    int l = r >> 3, j = r & 7;
    int oc = l & 15, k = ((l >> 4) << 3) + j;
    float v = 0.f;
    if (k < 27) {
      int kx = k / 9, rem = k % 9;
      int ky = rem / 3, ic = rem % 3;
      v = w1[oc * 27 + ic * 9 + ky * 3 + kx];
    }
    __bf16 hi = (__bf16)v;
    wsb[C1P_OFF + q] = f ? (__bf16)(v - (float)hi) : hi;
  }
}

// -------------------------------------------------------------- fused CNN
// R16 numerics, barrier-reduced layout. 1 image/block, 4 waves.
// LDS = 29472 B with DISJOINT s_img/s2 and s2/s3 regions so the barriers
// that only guarded LDS reuse are deleted (6 -> 4 per image):
//   s_img @0      (9248B; cell = 4 ush [ic0,ic1,ic2,0])
//   s2    @9248   (18 rows x 448 ush = 16128B; cell 24 ush, hi only)
//   s3    @0      (10 rows x 448 ush = 8960B; cell 40 ush) — reuses dead s_img
//   h3s   @25376  (4096B f32 [oc][py][px])
// Kept barriers: post-staging, pre-conv2, pre-conv3, pre-fc (true cross-wave
// deps). h1->s2 and h2->s3 writes now overlap other waves' compute.
// launch_bounds (256,4) -> 64-VGPR budget (empirical: ~512/(2*minwaves)).
__global__ __launch_bounds__(256, 4) void cnn_fused(
    const float* __restrict__ x, const __bf16* __restrict__ wsb,
    const float* __restrict__ b1, const float* __restrict__ b2,
    const float* __restrict__ b3,
    const float* __restrict__ fcw, const float* __restrict__ fcb,
    float* __restrict__ out) {
  __shared__ __align__(16) unsigned char smem[29472];
  __bf16* s_img = (__bf16*)smem;
  __bf16* s2b   = (__bf16*)(smem + 9248);
  __bf16* s3b   = (__bf16*)smem;
  float*  h3s   = (float*)(smem + 25376);

  const __bf16* b2p = wsb + B2P_OFF;
  const __bf16* b3p = wsb + B3P_OFF;
  const __bf16* c1p = wsb + C1P_OFF;

  const int tid = threadIdx.x;
  const int img = blockIdx.x;
  const int w = tid >> 6, lane = tid & 63;

  // ---- phase 1: zero s_img halo (132 cells) + write interior (disjoint)
  if (tid < 132) {
    int row, col;
    if (tid < 34)       { row = 0;        col = tid; }
    else if (tid < 68)  { row = 33;       col = tid - 34; }
    else if (tid < 100) { row = tid - 67; col = 0; }
    else                { row = tid - 99; col = 33; }
    *(unsigned long long*)&s_img[(row * 34 + col) * 4] = 0ull;
  }
  const float* xg = x + img * 3072;
  for (int i = tid; i < 1024; i += 256) {
    const int y = i >> 5, xx = i & 31;
    bf16x4 pk;
    pk.x = (__bf16)xg[i];
    pk.y = (__bf16)xg[i + 1024];
    pk.z = (__bf16)xg[i + 2048];
    pk.w = (__bf16)0.f;
    *(bf16x4*)&s_img[((y + 1) * 34 + (xx + 1)) * 4] = pk;
  }
  // s2 halo zero — disjoint from s_img, safe before the barrier
  if (tid >= 132 && tid < 200) {
    int c = tid - 132;
    int row, col;
    if (c < 18)      { row = 0;       col = c; }
    else if (c < 36) { row = 17;      col = c - 18; }
    else if (c < 52) { row = c - 35;  col = 0; }
    else             { row = c - 51;  col = 17; }
    unsigned long long* p = (unsigned long long*)&s2b[row * 448 + col * 24];
    p[0] = 0ull; p[1] = 0ull; p[2] = 0ull; p[3] = 0ull;
  }
  const bf16x8 B1h = *(const bf16x8*)(c1p + lane * 8);
  __syncthreads();                       // barrier 1: staging complete

  // ---- conv1: K=27-in-32 packed MFMA, 1-term (R15-validated)
  float pooled[16];
  {
    const int xm = lane & 15, kg = lane >> 4;
    #pragma unroll
    for (int p = 0; p < 4; ++p) {
      f32x4 acc[2][2];
      #pragma unroll
      for (int ys = 0; ys < 2; ++ys)
        #pragma unroll
        for (int xh = 0; xh < 2; ++xh)
          #pragma unroll
          for (int r = 0; r < 4; ++r) acc[ys][xh][r] = 0.f;
      #pragma unroll
      for (int ys = 0; ys < 2; ++ys) {
        const int yqg = w * 8 + p * 2 + ys;
        #pragma unroll
        for (int xh = 0; xh < 2; ++xh) {
          const int xv = xh * 16 + xm;
          const int ca = xv + (kg <= 1 ? 0 : kg - 1);
          const int cb = xv + (kg < 2 ? 1 : 2);
          const uint2 qa0 = *(const uint2*)&s_img[((yqg + 0) * 34 + ca) * 4];
          const uint2 qa1 = *(const uint2*)&s_img[((yqg + 1) * 34 + ca) * 4];
          const uint2 qa2 = *(const uint2*)&s_img[((yqg + 2) * 34 + ca) * 4];
          const uint2 qb0 = *(const uint2*)&s_img[((yqg + 0) * 34 + cb) * 4];
          const uint2 qb1 = *(const uint2*)&s_img[((yqg + 1) * 34 + cb) * 4];
          const uint2 qb2 = *(const uint2*)&s_img[((yqg + 2) * 34 + cb) * 4];
          const uint a0 = qa0.x, a1 = qa0.y, a2 = qa1.x, a3 = qa1.y, a4 = qa2.x, a5 = qa2.y;
          const uint b0 = qb0.x, b1 = qb0.y, b2 = qb1.x, b3 = qb1.y, b4 = qb2.x;
          U4B8 A;
          A.u.x = kg == 0 ? a0
                : kg == 1 ? (a5 | (b0 << 16))
                : kg == 2 ? ((a4 >> 16) | (a5 << 16))
                :           a4;
          A.u.y = kg == 0 ? (a1 | (a2 << 16))
                : kg == 1 ? ((b0 >> 16) | (b1 << 16))
                : kg == 2 ? b0
                :           a5;
          A.u.z = kg == 0 ? ((a2 >> 16) | (a3 << 16))
                : kg == 1 ? b2
                : kg == 2 ? (b1 | (b2 << 16))
                :           0u;
          A.u.w = kg == 0 ? a4
                : kg == 1 ? (b3 | (b4 << 16))
                : kg == 2 ? ((b2 >> 16) | (b3 << 16))
                :           0u;
          acc[ys][xh] = __builtin_amdgcn_mfma_f32_16x16x32_bf16(A.b, B1h, acc[ys][xh], 0, 0, 0);
        }
      }
      #pragma unroll
      for (int xh = 0; xh < 2; ++xh)
        #pragma unroll
        for (int xp2 = 0; xp2 < 2; ++xp2) {
          const float v0 = fmaxf(acc[0][xh][xp2 * 2], acc[0][xh][xp2 * 2 + 1]);
          const float v1 = fmaxf(acc[1][xh][xp2 * 2], acc[1][xh][xp2 * 2 + 1]);
          pooled[p * 4 + xh * 2 + xp2] = fmaxf(v0, v1);
        }
    }
  }
  // NO barrier: h1 writes go to s2 (disjoint from s_img other waves read)

  // ---- h1 (bias+relu, bf16 hi only) -> s2 (row stride 448, cell 24)
  {
    const int oc = lane & 15, quad = lane >> 4;
    const float bias = b1[oc];
    #pragma unroll
    for (int p = 0; p < 4; ++p)
      #pragma unroll
      for (int xh = 0; xh < 2; ++xh)
        #pragma unroll
        for (int xp2 = 0; xp2 < 2; ++xp2) {
          const float v = fmaxf(pooled[p * 4 + xh * 2 + xp2] + bias, 0.f);
          const int py = w * 4 + p, px = xh * 8 + quad * 2 + xp2;
          s2b[(py + 1) * 448 + (px + 1) * 24 + oc] = (__bf16)v;
        }
  }
  bf16x8 Bf[18];
  #pragma unroll
  for (int f = 0; f < 18; ++f)
    Bf[f] = *(const bf16x8*)(b2p + f * 512 + lane * 8);
  __syncthreads();                       // barrier 2: h1 complete

  // ---- conv2 (2-term), y-halves sequential (one f32x16 acc alive)
  float pooled2[8];
  {
    const unsigned short* s2 = (const unsigned short*)s2b;
    const int xm = lane & 15, yoff = (lane >> 4) & 1, kh = lane >> 5;
    #pragma unroll
    for (int i2 = 0; i2 < 2; ++i2) {
      f32x16v acc;
      #pragma unroll
      for (int r = 0; r < 16; ++r) acc[r] = 0.f;
      const int rbase = (4 * w + yoff + 2 * i2) * 448;
      #pragma unroll
      for (int t = 0; t < 9; ++t) {
        const int ky = t / 3, kx = t % 3;
        const int ro = rbase + ky * 448 + (xm + kx) * 24 + kh * 8;
        bf16x8 ah = *(const bf16x8*)&s2[ro];
        acc = __builtin_amdgcn_mfma_f32_32x32x16_bf16(ah, Bf[t * 2],     acc, 0, 0, 0);
        acc = __builtin_amdgcn_mfma_f32_32x32x16_bf16(ah, Bf[t * 2 + 1], acc, 0, 0, 0);
      }
      #pragma unroll
      for (int bq = 0; bq < 2; ++bq)
        #pragma unroll
        for (int rq = 0; rq < 2; ++rq) {
          const int r0 = bq * 4 + rq * 2;
          pooled2[i2 * 4 + bq * 2 + rq] =
              fmaxf(fmaxf(acc[r0], acc[r0 + 1]), fmaxf(acc[r0 + 8], acc[r0 + 9]));
        }
    }
  }
  // NO barrier: h2 writes go to s3 (@0, disjoint from s2 other waves read)

  // ---- h2 (bias+relu, bf16 hi only) -> s3 (row stride 448, cell 40)
  if (tid < 36) {
    int row, col;
    if (tid < 10)      { row = 0;       col = tid; }
    else if (tid < 20) { row = 9;       col = tid - 10; }
    else if (tid < 28) { row = tid - 19; col = 0; }
    else               { row = tid - 27; col = 9; }
    unsigned long long* p = (unsigned long long*)&s3b[row * 448 + col * 40];
    #pragma unroll
    for (int u = 0; u < 8; ++u) p[u] = 0ull;
  }
  {
    const int oc = lane & 31, hh = lane >> 5;
    const float bias = b2[oc];
    #pragma unroll
    for (int i2 = 0; i2 < 2; ++i2)
      #pragma unroll
      for (int bq = 0; bq < 2; ++bq)
        #pragma unroll
        for (int rq = 0; rq < 2; ++rq) {
          const float v = fmaxf(pooled2[i2 * 4 + bq * 2 + rq] + bias, 0.f);
          const int py = 2 * w + i2, px = 2 * hh + 4 * bq + rq;
          s3b[(py + 1) * 448 + (px + 1) * 40 + oc] = (__bf16)v;
        }
  }
  __syncthreads();                       // barrier 3: h2 complete

  // ---- conv3 (wave = nt = oc-tile), 2-term
  {
    const unsigned short* s3 = (const unsigned short*)s3b;
    const int nt = w;
    bf16x8 Bt[18];
    #pragma unroll
    for (int t = 0; t < 9; ++t) {
      Bt[t * 2]     = *(const bf16x8*)(b3p + (t * 8 + nt * 2) * 512 + lane * 8);
      Bt[t * 2 + 1] = *(const bf16x8*)(b3p + (t * 8 + nt * 2 + 1) * 512 + lane * 8);
    }
    const int m = lane & 15, quad = lane >> 4;
    const int xm = m & 7, yoff = m >> 3;
    f32x4 acc[4];
    #pragma unroll
    for (int mt = 0; mt < 4; ++mt)
      #pragma unroll
      for (int r = 0; r < 4; ++r) acc[mt][r] = 0.f;
    #pragma unroll
    for (int t = 0; t < 9; ++t) {
      const int ky = t / 3, kx = t % 3;
      #pragma unroll
      for (int mt = 0; mt < 4; ++mt) {
        const int ro = (2 * mt + yoff + ky) * 448 + (xm + kx) * 40 + quad * 8;
        bf16x8 ah = *(const bf16x8*)&s3[ro];
        acc[mt] = __builtin_amdgcn_mfma_f32_16x16x32_bf16(ah, Bt[t * 2],     acc[mt], 0, 0, 0);
        acc[mt] = __builtin_amdgcn_mfma_f32_16x16x32_bf16(ah, Bt[t * 2 + 1], acc[mt], 0, 0, 0);
      }
    }
    // epilogue -> h3s (@25376, disjoint from s3)
    const int ocl = lane & 15;
    #pragma unroll
    for (int mt = 0; mt < 4; ++mt) {
      float p0 = fmaxf(acc[mt][0], acc[mt][1]);
      float p1 = fmaxf(acc[mt][2], acc[mt][3]);
      p0 = fmaxf(p0, __shfl_xor(p0, 32, 64));
      p1 = fmaxf(p1, __shfl_xor(p1, 32, 64));
      if (quad < 2) {
        const int oc = nt * 16 + ocl;
        const float bias = b3[oc];
        const int base = oc * 16 + mt * 4 + (quad & 1) * 2;
        h3s[base]     = fmaxf(p0 + bias, 0.f);
        h3s[base + 1] = fmaxf(p1 + bias, 0.f);
      }
    }
  }
  __syncthreads();                       // barrier 4: h3 complete

  // ---- fc: all 4 waves, wave w handles outputs j = w, w+4, ...
  {
    float hv[16];
    #pragma unroll
    for (int i = 0; i < 16; ++i) hv[i] = h3s[i * 64 + lane];
    for (int j = w; j < 10; j += 4) {
      float dot = 0.f;
      #pragma unroll
      for (int i = 0; i < 16; ++i)
        dot = fmaf(hv[i], fcw[j * 1024 + i * 64 + lane], dot);
      #pragma unroll
      for (int s = 32; s > 0; s >>= 1) dot += __shfl_xor(dot, s, 64);
      if (lane == 0) out[img * 10 + j] = dot + fcb[j];
    }
  }
}

// -------------------------------------------------------------------- launch
extern "C" void kernel_launch(void* const* d_in, const int* in_sizes, int n_in,
                              void* d_out, int out_size, void* d_ws, size_t ws_size,
                              hipStream_t stream) {
  const float* x   = (const float*)d_in[0];
  const float* w1  = (const float*)d_in[1];
  const float* b1  = (const float*)d_in[2];
  const float* w2  = (const float*)d_in[3];
  const float* b2  = (const float*)d_in[4];
  const float* w3  = (const float*)d_in[5];
  const float* b3  = (const float*)d_in[6];
  const float* fcw = (const float*)d_in[7];
  const float* fcb = (const float*)d_in[8];
  __bf16* wsb = (__bf16*)d_ws;
  float* out = (float*)d_out;

  hipLaunchKernelGGL(pack_weights, dim3(184), dim3(256), 0, stream, w1, w2, w3, wsb);
  hipLaunchKernelGGL(cnn_fused, dim3(4096), dim3(256), 0, stream,
                     x, wsb, b1, b2, b3, fcw, fcb, out);
}

// Round 18
// 135.761 us; speedup vs baseline: 1.3116x; 1.1232x over previous
//
#include <hip/hip_runtime.h>

typedef float f32x4 __attribute__((ext_vector_type(4)));
typedef float f32x16v __attribute__((ext_vector_type(16)));
typedef __bf16 bf16x4 __attribute__((ext_vector_type(4)));
typedef __bf16 bf16x8 __attribute__((ext_vector_type(8)));

union U4B8 { uint4 u; bf16x8 b; };

// ws layout (bf16 elements): b2p[9216] @0, b3p[36864] @9216, c1p[1024] @46080
#define B2P_OFF 0
#define B3P_OFF 9216
#define C1P_OFF 46080

// ------------------------------------------------------------- pack_weights
// (unchanged; lo-frags still packed but no longer read — kernels use RNE hi)
__global__ __launch_bounds__(256) void pack_weights(
    const float* __restrict__ w1, const float* __restrict__ w2,
    const float* __restrict__ w3, __bf16* __restrict__ wsb) {
  int i = blockIdx.x * 256 + threadIdx.x;
  if (i < 9216) {
    int f = i >> 9, r = i & 511;
    int l = r >> 3, j = r & 7;
    int t = f >> 1, p = f & 1;
    int ky = t / 3, kx = t % 3;
    int oc = l & 31, ic = ((l >> 5) << 3) + j;
    float v = w2[oc * 144 + ic * 9 + ky * 3 + kx];
    __bf16 hi = (__bf16)v;
    wsb[B2P_OFF + i] = p ? (__bf16)(v - (float)hi) : hi;
  } else if (i < 9216 + 36864) {
    int q = i - 9216;
    int f = q >> 9, r = q & 511;
    int l = r >> 3, j = r & 7;
    int t = f >> 3, nt = (f >> 1) & 3, p = f & 1;
    int ky = t / 3, kx = t % 3;
    int oc = nt * 16 + (l & 15), ic = ((l >> 4) << 3) + j;
    float v = w3[oc * 288 + ic * 9 + ky * 3 + kx];
    __bf16 hi = (__bf16)v;
    wsb[B3P_OFF + q] = p ? (__bf16)(v - (float)hi) : hi;
  } else if (i < 9216 + 36864 + 1024) {
    int q = i - (9216 + 36864);
    int f = q >> 9, r = q & 511;
    int l = r >> 3, j = r & 7;
    int oc = l & 15, k = ((l >> 4) << 3) + j;
    float v = 0.f;
    if (k < 27) {
      int kx = k / 9, rem = k % 9;
      int ky = rem / 3, ic = rem % 3;
      v = w1[oc * 27 + ic * 9 + ky * 3 + kx];
    }
    __bf16 hi = (__bf16)v;
    wsb[C1P_OFF + q] = f ? (__bf16)(v - (float)hi) : hi;
  }
}

// -------------------------------------------------------------- fused CNN
// R17 layout; NEW: conv2/conv3 fully 1-term (a_h * b_rne) — MFMA count
// halved (error: activation-rounding-dominated; weight-rounding adds
// ~sqrt2-2x -> ~0.012-0.016 vs 0.034 threshold). Staging loads float4.
//   s_img @0      (9248B)   s2 @9248 (16128B)   s3 @0 (8960B)
//   h3s   @25376  (4096B f32)
__global__ __launch_bounds__(256, 4) void cnn_fused(
    const float* __restrict__ x, const __bf16* __restrict__ wsb,
    const float* __restrict__ b1, const float* __restrict__ b2,
    const float* __restrict__ b3,
    const float* __restrict__ fcw, const float* __restrict__ fcb,
    float* __restrict__ out) {
  __shared__ __align__(16) unsigned char smem[29472];
  __bf16* s_img = (__bf16*)smem;
  __bf16* s2b   = (__bf16*)(smem + 9248);
  __bf16* s3b   = (__bf16*)smem;
  float*  h3s   = (float*)(smem + 25376);

  const __bf16* b2p = wsb + B2P_OFF;
  const __bf16* b3p = wsb + B3P_OFF;
  const __bf16* c1p = wsb + C1P_OFF;

  const int tid = threadIdx.x;
  const int img = blockIdx.x;
  const int w = tid >> 6, lane = tid & 63;

  // ---- phase 1: halo zero + float4-vectorized interior staging
  if (tid < 132) {
    int row, col;
    if (tid < 34)       { row = 0;        col = tid; }
    else if (tid < 68)  { row = 33;       col = tid - 34; }
    else if (tid < 100) { row = tid - 67; col = 0; }
    else                { row = tid - 99; col = 33; }
    *(unsigned long long*)&s_img[(row * 34 + col) * 4] = 0ull;
  }
  {
    const float* xg = x + img * 3072;
    const int r = tid * 4;               // 4 consecutive pixels per thread
    const int y = r >> 5, xx = r & 31;
    const f32x4 c0 = *(const f32x4*)&xg[r];
    const f32x4 c1 = *(const f32x4*)&xg[r + 1024];
    const f32x4 c2 = *(const f32x4*)&xg[r + 2048];
    #pragma unroll
    for (int k = 0; k < 4; ++k) {
      bf16x4 pk;
      pk.x = (__bf16)c0[k];
      pk.y = (__bf16)c1[k];
      pk.z = (__bf16)c2[k];
      pk.w = (__bf16)0.f;
      *(bf16x4*)&s_img[((y + 1) * 34 + (xx + k + 1)) * 4] = pk;
    }
  }
  // s2 halo zero — disjoint from s_img
  if (tid >= 132 && tid < 200) {
    int c = tid - 132;
    int row, col;
    if (c < 18)      { row = 0;       col = c; }
    else if (c < 36) { row = 17;      col = c - 18; }
    else if (c < 52) { row = c - 35;  col = 0; }
    else             { row = c - 51;  col = 17; }
    unsigned long long* p = (unsigned long long*)&s2b[row * 448 + col * 24];
    p[0] = 0ull; p[1] = 0ull; p[2] = 0ull; p[3] = 0ull;
  }
  const bf16x8 B1h = *(const bf16x8*)(c1p + lane * 8);
  __syncthreads();                       // barrier 1: staging complete

  // ---- conv1: K=27-in-32 packed MFMA, 1-term (R15-validated)
  float pooled[16];
  {
    const int xm = lane & 15, kg = lane >> 4;
    #pragma unroll
    for (int p = 0; p < 4; ++p) {
      f32x4 acc[2][2];
      #pragma unroll
      for (int ys = 0; ys < 2; ++ys)
        #pragma unroll
        for (int xh = 0; xh < 2; ++xh)
          #pragma unroll
          for (int r = 0; r < 4; ++r) acc[ys][xh][r] = 0.f;
      #pragma unroll
      for (int ys = 0; ys < 2; ++ys) {
        const int yqg = w * 8 + p * 2 + ys;
        #pragma unroll
        for (int xh = 0; xh < 2; ++xh) {
          const int xv = xh * 16 + xm;
          const int ca = xv + (kg <= 1 ? 0 : kg - 1);
          const int cb = xv + (kg < 2 ? 1 : 2);
          const uint2 qa0 = *(const uint2*)&s_img[((yqg + 0) * 34 + ca) * 4];
          const uint2 qa1 = *(const uint2*)&s_img[((yqg + 1) * 34 + ca) * 4];
          const uint2 qa2 = *(const uint2*)&s_img[((yqg + 2) * 34 + ca) * 4];
          const uint2 qb0 = *(const uint2*)&s_img[((yqg + 0) * 34 + cb) * 4];
          const uint2 qb1 = *(const uint2*)&s_img[((yqg + 1) * 34 + cb) * 4];
          const uint2 qb2 = *(const uint2*)&s_img[((yqg + 2) * 34 + cb) * 4];
          const uint a0 = qa0.x, a1 = qa0.y, a2 = qa1.x, a3 = qa1.y, a4 = qa2.x, a5 = qa2.y;
          const uint b0 = qb0.x, b1 = qb0.y, b2 = qb1.x, b3 = qb1.y, b4 = qb2.x;
          U4B8 A;
          A.u.x = kg == 0 ? a0
                : kg == 1 ? (a5 | (b0 << 16))
                : kg == 2 ? ((a4 >> 16) | (a5 << 16))
                :           a4;
          A.u.y = kg == 0 ? (a1 | (a2 << 16))
                : kg == 1 ? ((b0 >> 16) | (b1 << 16))
                : kg == 2 ? b0
                :           a5;
          A.u.z = kg == 0 ? ((a2 >> 16) | (a3 << 16))
                : kg == 1 ? b2
                : kg == 2 ? (b1 | (b2 << 16))
                :           0u;
          A.u.w = kg == 0 ? a4
                : kg == 1 ? (b3 | (b4 << 16))
                : kg == 2 ? ((b2 >> 16) | (b3 << 16))
                :           0u;
          acc[ys][xh] = __builtin_amdgcn_mfma_f32_16x16x32_bf16(A.b, B1h, acc[ys][xh], 0, 0, 0);
        }
      }
      #pragma unroll
      for (int xh = 0; xh < 2; ++xh)
        #pragma unroll
        for (int xp2 = 0; xp2 < 2; ++xp2) {
          const float v0 = fmaxf(acc[0][xh][xp2 * 2], acc[0][xh][xp2 * 2 + 1]);
          const float v1 = fmaxf(acc[1][xh][xp2 * 2], acc[1][xh][xp2 * 2 + 1]);
          pooled[p * 4 + xh * 2 + xp2] = fmaxf(v0, v1);
        }
    }
  }
  // no barrier: h1 -> s2 disjoint from s_img

  // ---- h1 (bias+relu, bf16 hi only) -> s2 (row stride 448, cell 24)
  {
    const int oc = lane & 15, quad = lane >> 4;
    const float bias = b1[oc];
    #pragma unroll
    for (int p = 0; p < 4; ++p)
      #pragma unroll
      for (int xh = 0; xh < 2; ++xh)
        #pragma unroll
        for (int xp2 = 0; xp2 < 2; ++xp2) {
          const float v = fmaxf(pooled[p * 4 + xh * 2 + xp2] + bias, 0.f);
          const int py = w * 4 + p, px = xh * 8 + quad * 2 + xp2;
          s2b[(py + 1) * 448 + (px + 1) * 24 + oc] = (__bf16)v;
        }
  }
  bf16x8 Bf[9];                          // RNE weights only (1-term)
  #pragma unroll
  for (int t = 0; t < 9; ++t)
    Bf[t] = *(const bf16x8*)(b2p + (t * 2) * 512 + lane * 8);
  __syncthreads();                       // barrier 2: h1 complete

  // ---- conv2 (1-term), y-halves sequential (one f32x16 acc alive)
  float pooled2[8];
  {
    const unsigned short* s2 = (const unsigned short*)s2b;
    const int xm = lane & 15, yoff = (lane >> 4) & 1, kh = lane >> 5;
    #pragma unroll
    for (int i2 = 0; i2 < 2; ++i2) {
      f32x16v acc;
      #pragma unroll
      for (int r = 0; r < 16; ++r) acc[r] = 0.f;
      const int rbase = (4 * w + yoff + 2 * i2) * 448;
      #pragma unroll
      for (int t = 0; t < 9; ++t) {
        const int ky = t / 3, kx = t % 3;
        const int ro = rbase + ky * 448 + (xm + kx) * 24 + kh * 8;
        bf16x8 ah = *(const bf16x8*)&s2[ro];
        acc = __builtin_amdgcn_mfma_f32_32x32x16_bf16(ah, Bf[t], acc, 0, 0, 0);
      }
      #pragma unroll
      for (int bq = 0; bq < 2; ++bq)
        #pragma unroll
        for (int rq = 0; rq < 2; ++rq) {
          const int r0 = bq * 4 + rq * 2;
          pooled2[i2 * 4 + bq * 2 + rq] =
              fmaxf(fmaxf(acc[r0], acc[r0 + 1]), fmaxf(acc[r0 + 8], acc[r0 + 9]));
        }
    }
  }
  // no barrier: h2 -> s3 (@0) disjoint from s2

  // ---- h2 (bias+relu, bf16 hi only) -> s3 (row stride 448, cell 40)
  if (tid < 36) {
    int row, col;
    if (tid < 10)      { row = 0;       col = tid; }
    else if (tid < 20) { row = 9;       col = tid - 10; }
    else if (tid < 28) { row = tid - 19; col = 0; }
    else               { row = tid - 27; col = 9; }
    unsigned long long* p = (unsigned long long*)&s3b[row * 448 + col * 40];
    #pragma unroll
    for (int u = 0; u < 8; ++u) p[u] = 0ull;
  }
  {
    const int oc = lane & 31, hh = lane >> 5;
    const float bias = b2[oc];
    #pragma unroll
    for (int i2 = 0; i2 < 2; ++i2)
      #pragma unroll
      for (int bq = 0; bq < 2; ++bq)
        #pragma unroll
        for (int rq = 0; rq < 2; ++rq) {
          const float v = fmaxf(pooled2[i2 * 4 + bq * 2 + rq] + bias, 0.f);
          const int py = 2 * w + i2, px = 2 * hh + 4 * bq + rq;
          s3b[(py + 1) * 448 + (px + 1) * 40 + oc] = (__bf16)v;
        }
  }
  __syncthreads();                       // barrier 3: h2 complete

  // ---- conv3 (wave = nt = oc-tile), 1-term
  {
    const unsigned short* s3 = (const unsigned short*)s3b;
    const int nt = w;
    bf16x8 Bt[9];
    #pragma unroll
    for (int t = 0; t < 9; ++t)
      Bt[t] = *(const bf16x8*)(b3p + (t * 8 + nt * 2) * 512 + lane * 8);
    const int m = lane & 15, quad = lane >> 4;
    const int xm = m & 7, yoff = m >> 3;
    f32x4 acc[4];
    #pragma unroll
    for (int mt = 0; mt < 4; ++mt)
      #pragma unroll
      for (int r = 0; r < 4; ++r) acc[mt][r] = 0.f;
    #pragma unroll
    for (int t = 0; t < 9; ++t) {
      const int ky = t / 3, kx = t % 3;
      #pragma unroll
      for (int mt = 0; mt < 4; ++mt) {
        const int ro = (2 * mt + yoff + ky) * 448 + (xm + kx) * 40 + quad * 8;
        bf16x8 ah = *(const bf16x8*)&s3[ro];
        acc[mt] = __builtin_amdgcn_mfma_f32_16x16x32_bf16(ah, Bt[t], acc[mt], 0, 0, 0);
      }
    }
    // epilogue -> h3s (@25376, disjoint from s3)
    const int ocl = lane & 15;
    #pragma unroll
    for (int mt = 0; mt < 4; ++mt) {
      float p0 = fmaxf(acc[mt][0], acc[mt][1]);
      float p1 = fmaxf(acc[mt][2], acc[mt][3]);
      p0 = fmaxf(p0, __shfl_xor(p0, 32, 64));
      p1 = fmaxf(p1, __shfl_xor(p1, 32, 64));
      if (quad < 2) {
        const int oc = nt * 16 + ocl;
        const float bias = b3[oc];
        const int base = oc * 16 + mt * 4 + (quad & 1) * 2;
        h3s[base]     = fmaxf(p0 + bias, 0.f);
        h3s[base + 1] = fmaxf(p1 + bias, 0.f);
      }
    }
  }
  __syncthreads();                       // barrier 4: h3 complete

  // ---- fc: all 4 waves, wave w handles outputs j = w, w+4, ...
  {
    float hv[16];
    #pragma unroll
    for (int i = 0; i < 16; ++i) hv[i] = h3s[i * 64 + lane];
    for (int j = w; j < 10; j += 4) {
      float dot = 0.f;
      #pragma unroll
      for (int i = 0; i < 16; ++i)
        dot = fmaf(hv[i], fcw[j * 1024 + i * 64 + lane], dot);
      #pragma unroll
      for (int s = 32; s > 0; s >>= 1) dot += __shfl_xor(dot, s, 64);
      if (lane == 0) out[img * 10 + j] = dot + fcb[j];
    }
  }
}

// -------------------------------------------------------------------- launch
extern "C" void kernel_launch(void* const* d_in, const int* in_sizes, int n_in,
                              void* d_out, int out_size, void* d_ws, size_t ws_size,
                              hipStream_t stream) {
  const float* x   = (const float*)d_in[0];
  const float* w1  = (const float*)d_in[1];
  const float* b1  = (const float*)d_in[2];
  const float* w2  = (const float*)d_in[3];
  const float* b2  = (const float*)d_in[4];
  const float* w3  = (const float*)d_in[5];
  const float* b3  = (const float*)d_in[6];
  const float* fcw = (const float*)d_in[7];
  const float* fcb = (const float*)d_in[8];
  __bf16* wsb = (__bf16*)d_ws;
  float* out = (float*)d_out;

  hipLaunchKernelGGL(pack_weights, dim3(184), dim3(256), 0, stream, w1, w2, w3, wsb);
  hipLaunchKernelGGL(cnn_fused, dim3(4096), dim3(256), 0, stream,
                     x, wsb, b1, b2, b3, fcw, fcb, out);
}

// Round 19
// 126.549 us; speedup vs baseline: 1.4071x; 1.0728x over previous
//
#include <hip/hip_runtime.h>

typedef float f32x4 __attribute__((ext_vector_type(4)));
typedef float f32x16v __attribute__((ext_vector_type(16)));
typedef __bf16 bf16x4 __attribute__((ext_vector_type(4)));
typedef __bf16 bf16x8 __attribute__((ext_vector_type(8)));

union U4B8 { uint4 u; bf16x8 b; };

// ws layout (bf16 elements): b2p[9216] @0, b3p[36864] @9216, c1p[1024] @46080
#define B2P_OFF 0
#define B3P_OFF 9216
#define C1P_OFF 46080

// ------------------------------------------------------------- pack_weights
// b2p frag f=t*2+p: lane l, j: oc=l&31, ic=(l>>5)*8+j              (32x32x16)
// b3p frag f=t*8+nt*2+p: lane l, j: oc=nt*16+(l&15), ic=(l>>4)*8+j (16x16x32)
// c1p NEW (R19): A-frag = two horizontally-adjacent s_img cells.
//   j: half=j>>2, ic=j&3 (ic==3 -> pad=0). lane l: oc=l&15, kg=l>>4.
//   B1 (f=0): kg<3 -> w1[oc][ic][ky=kg][kx=half]; kg==3 -> half==0 ?
//             w1[oc][ic][0][2] : 0.
//   B2 (f=1): half==0 && kg<2 -> w1[oc][ic][kg+1][2] : 0.
__global__ __launch_bounds__(256) void pack_weights(
    const float* __restrict__ w1, const float* __restrict__ w2,
    const float* __restrict__ w3, __bf16* __restrict__ wsb) {
  int i = blockIdx.x * 256 + threadIdx.x;
  if (i < 9216) {
    int f = i >> 9, r = i & 511;
    int l = r >> 3, j = r & 7;
    int t = f >> 1, p = f & 1;
    int ky = t / 3, kx = t % 3;
    int oc = l & 31, ic = ((l >> 5) << 3) + j;
    float v = w2[oc * 144 + ic * 9 + ky * 3 + kx];
    __bf16 hi = (__bf16)v;
    wsb[B2P_OFF + i] = p ? (__bf16)(v - (float)hi) : hi;
  } else if (i < 9216 + 36864) {
    int q = i - 9216;
    int f = q >> 9, r = q & 511;
    int l = r >> 3, j = r & 7;
    int t = f >> 3, nt = (f >> 1) & 3, p = f & 1;
    int ky = t / 3, kx = t % 3;
    int oc = nt * 16 + (l & 15), ic = ((l >> 4) << 3) + j;
    float v = w3[oc * 288 + ic * 9 + ky * 3 + kx];
    __bf16 hi = (__bf16)v;
    wsb[B3P_OFF + q] = p ? (__bf16)(v - (float)hi) : hi;
  } else if (i < 9216 + 36864 + 1024) {
    int q = i - (9216 + 36864);
    int f = q >> 9, r = q & 511;
    int l = r >> 3, j = r & 7;
    int oc = l & 15, kg = l >> 4;
    int half = j >> 2, ic = j & 3;
    float v = 0.f;
    if (ic < 3) {
      if (f == 0) {
        if (kg < 3)            v = w1[oc * 27 + ic * 9 + kg * 3 + half];
        else if (half == 0)    v = w1[oc * 27 + ic * 9 + 0 * 3 + 2];
      } else {
        if (half == 0 && kg < 2) v = w1[oc * 27 + ic * 9 + (kg + 1) * 3 + 2];
      }
    }
    wsb[C1P_OFF + q] = (__bf16)v;
  }
}

// -------------------------------------------------------------- fused CNN
// R18 + select-free conv1 A-build (cell-pair k-mapping, 2 MFMA/build).
//   s_img @0     (9280B = 4640 ush: 34x34 cells + 16-ush zero pad)
//   s2    @9280  (16128B)   s3 @0 (8960B)   h3s @25408 (4096B)
__global__ __launch_bounds__(256, 4) void cnn_fused(
    const float* __restrict__ x, const __bf16* __restrict__ wsb,
    const float* __restrict__ b1, const float* __restrict__ b2,
    const float* __restrict__ b3,
    const float* __restrict__ fcw, const float* __restrict__ fcb,
    float* __restrict__ out) {
  __shared__ __align__(16) unsigned char smem[29504];
  __bf16* s_img = (__bf16*)smem;
  __bf16* s2b   = (__bf16*)(smem + 9280);
  __bf16* s3b   = (__bf16*)smem;
  float*  h3s   = (float*)(smem + 25408);

  const __bf16* b2p = wsb + B2P_OFF;
  const __bf16* b3p = wsb + B3P_OFF;
  const __bf16* c1p = wsb + C1P_OFF;

  const int tid = threadIdx.x;
  const int img = blockIdx.x;
  const int w = tid >> 6, lane = tid & 63;

  // ---- phase 1: halo zero (132 cells) + end pad + float4 staging
  if (tid < 132) {
    int row, col;
    if (tid < 34)       { row = 0;        col = tid; }
    else if (tid < 68)  { row = 33;       col = tid - 34; }
    else if (tid < 100) { row = tid - 67; col = 0; }
    else                { row = tid - 99; col = 33; }
    *(unsigned long long*)&s_img[(row * 34 + col) * 4] = 0ull;
  } else if (tid >= 248 && tid < 252) {
    *(unsigned long long*)&s_img[4624 + (tid - 248) * 4] = 0ull;  // pad
  }
  {
    const float* xg = x + img * 3072;
    const int r = tid * 4;
    const int y = r >> 5, xx = r & 31;
    const f32x4 c0 = *(const f32x4*)&xg[r];
    const f32x4 c1 = *(const f32x4*)&xg[r + 1024];
    const f32x4 c2 = *(const f32x4*)&xg[r + 2048];
    #pragma unroll
    for (int k = 0; k < 4; ++k) {
      bf16x4 pk;
      pk.x = (__bf16)c0[k];
      pk.y = (__bf16)c1[k];
      pk.z = (__bf16)c2[k];
      pk.w = (__bf16)0.f;
      *(bf16x4*)&s_img[((y + 1) * 34 + (xx + k + 1)) * 4] = pk;
    }
  }
  // s2 halo zero — disjoint from s_img
  if (tid >= 132 && tid < 200) {
    int c = tid - 132;
    int row, col;
    if (c < 18)      { row = 0;       col = c; }
    else if (c < 36) { row = 17;      col = c - 18; }
    else if (c < 52) { row = c - 35;  col = 0; }
    else             { row = c - 51;  col = 17; }
    unsigned long long* p = (unsigned long long*)&s2b[row * 448 + col * 24];
    p[0] = 0ull; p[1] = 0ull; p[2] = 0ull; p[3] = 0ull;
  }
  const bf16x8 B1h = *(const bf16x8*)(c1p + lane * 8);
  const bf16x8 B2h = *(const bf16x8*)(c1p + 512 + lane * 8);
  __syncthreads();                       // barrier 1: staging complete

  // ---- conv1: select-free A-build. Per-lane cell-offset constants:
  //   A1 cells: (y+d1r, x+d1c), (.., +1);  A2 cells: (y+d2r, x+2), (.., +1)
  //   kg0:(0,0)/(1,2)  kg1:(1,0)/(2,2)  kg2:(2,0)/(2,2)  kg3:(0,2)/(2,2)
  float pooled[16];
  {
    const int xm = lane & 15, kg = lane >> 4;
    const int d1r = (kg == 3) ? 0 : kg;
    const int d1c = (kg == 3) ? 2 : 0;
    const int d2r = (kg == 0) ? 1 : 2;
    const int dd1 = d1r * 34 + d1c;
    const int dd2 = d2r * 34 + 2;
    #pragma unroll
    for (int p = 0; p < 4; ++p) {
      f32x4 acc[2][2];
      #pragma unroll
      for (int ys = 0; ys < 2; ++ys)
        #pragma unroll
        for (int xh = 0; xh < 2; ++xh)
          #pragma unroll
          for (int r = 0; r < 4; ++r) acc[ys][xh][r] = 0.f;
      #pragma unroll
      for (int ys = 0; ys < 2; ++ys) {
        const int yqg = w * 8 + p * 2 + ys;
        #pragma unroll
        for (int xh = 0; xh < 2; ++xh) {
          const int cb = yqg * 34 + xh * 16 + xm;
          const uint2 p0 = *(const uint2*)&s_img[(cb + dd1) * 4];
          const uint2 p1 = *(const uint2*)&s_img[(cb + dd1 + 1) * 4];
          const uint2 p2 = *(const uint2*)&s_img[(cb + dd2) * 4];
          const uint2 p3 = *(const uint2*)&s_img[(cb + dd2 + 1) * 4];
          U4B8 A1, A2;
          A1.u.x = p0.x; A1.u.y = p0.y; A1.u.z = p1.x; A1.u.w = p1.y;
          A2.u.x = p2.x; A2.u.y = p2.y; A2.u.z = p3.x; A2.u.w = p3.y;
          acc[ys][xh] = __builtin_amdgcn_mfma_f32_16x16x32_bf16(A1.b, B1h, acc[ys][xh], 0, 0, 0);
          acc[ys][xh] = __builtin_amdgcn_mfma_f32_16x16x32_bf16(A2.b, B2h, acc[ys][xh], 0, 0, 0);
        }
      }
      #pragma unroll
      for (int xh = 0; xh < 2; ++xh)
        #pragma unroll
        for (int xp2 = 0; xp2 < 2; ++xp2) {
          const float v0 = fmaxf(acc[0][xh][xp2 * 2], acc[0][xh][xp2 * 2 + 1]);
          const float v1 = fmaxf(acc[1][xh][xp2 * 2], acc[1][xh][xp2 * 2 + 1]);
          pooled[p * 4 + xh * 2 + xp2] = fmaxf(v0, v1);
        }
    }
  }
  // no barrier: h1 -> s2 disjoint from s_img

  // ---- h1 (bias+relu, bf16 hi only) -> s2 (row stride 448, cell 24)
  {
    const int oc = lane & 15, quad = lane >> 4;
    const float bias = b1[oc];
    #pragma unroll
    for (int p = 0; p < 4; ++p)
      #pragma unroll
      for (int xh = 0; xh < 2; ++xh)
        #pragma unroll
        for (int xp2 = 0; xp2 < 2; ++xp2) {
          const float v = fmaxf(pooled[p * 4 + xh * 2 + xp2] + bias, 0.f);
          const int py = w * 4 + p, px = xh * 8 + quad * 2 + xp2;
          s2b[(py + 1) * 448 + (px + 1) * 24 + oc] = (__bf16)v;
        }
  }
  bf16x8 Bf[9];
  #pragma unroll
  for (int t = 0; t < 9; ++t)
    Bf[t] = *(const bf16x8*)(b2p + (t * 2) * 512 + lane * 8);
  __syncthreads();                       // barrier 2: h1 complete

  // ---- conv2 (1-term), y-halves sequential
  float pooled2[8];
  {
    const unsigned short* s2 = (const unsigned short*)s2b;
    const int xm = lane & 15, yoff = (lane >> 4) & 1, kh = lane >> 5;
    #pragma unroll
    for (int i2 = 0; i2 < 2; ++i2) {
      f32x16v acc;
      #pragma unroll
      for (int r = 0; r < 16; ++r) acc[r] = 0.f;
      const int rbase = (4 * w + yoff + 2 * i2) * 448;
      #pragma unroll
      for (int t = 0; t < 9; ++t) {
        const int ky = t / 3, kx = t % 3;
        const int ro = rbase + ky * 448 + (xm + kx) * 24 + kh * 8;
        bf16x8 ah = *(const bf16x8*)&s2[ro];
        acc = __builtin_amdgcn_mfma_f32_32x32x16_bf16(ah, Bf[t], acc, 0, 0, 0);
      }
      #pragma unroll
      for (int bq = 0; bq < 2; ++bq)
        #pragma unroll
        for (int rq = 0; rq < 2; ++rq) {
          const int r0 = bq * 4 + rq * 2;
          pooled2[i2 * 4 + bq * 2 + rq] =
              fmaxf(fmaxf(acc[r0], acc[r0 + 1]), fmaxf(acc[r0 + 8], acc[r0 + 9]));
        }
    }
  }
  // no barrier: h2 -> s3 (@0) disjoint from s2

  // ---- h2 (bias+relu, bf16 hi only) -> s3 (row stride 448, cell 40)
  if (tid < 36) {
    int row, col;
    if (tid < 10)      { row = 0;       col = tid; }
    else if (tid < 20) { row = 9;       col = tid - 10; }
    else if (tid < 28) { row = tid - 19; col = 0; }
    else               { row = tid - 27; col = 9; }
    unsigned long long* p = (unsigned long long*)&s3b[row * 448 + col * 40];
    #pragma unroll
    for (int u = 0; u < 8; ++u) p[u] = 0ull;
  }
  {
    const int oc = lane & 31, hh = lane >> 5;
    const float bias = b2[oc];
    #pragma unroll
    for (int i2 = 0; i2 < 2; ++i2)
      #pragma unroll
      for (int bq = 0; bq < 2; ++bq)
        #pragma unroll
        for (int rq = 0; rq < 2; ++rq) {
          const float v = fmaxf(pooled2[i2 * 4 + bq * 2 + rq] + bias, 0.f);
          const int py = 2 * w + i2, px = 2 * hh + 4 * bq + rq;
          s3b[(py + 1) * 448 + (px + 1) * 40 + oc] = (__bf16)v;
        }
  }
  __syncthreads();                       // barrier 3: h2 complete

  // ---- conv3 (wave = nt = oc-tile), 1-term
  {
    const unsigned short* s3 = (const unsigned short*)s3b;
    const int nt = w;
    bf16x8 Bt[9];
    #pragma unroll
    for (int t = 0; t < 9; ++t)
      Bt[t] = *(const bf16x8*)(b3p + (t * 8 + nt * 2) * 512 + lane * 8);
    const int m = lane & 15, quad = lane >> 4;
    const int xm = m & 7, yoff = m >> 3;
    f32x4 acc[4];
    #pragma unroll
    for (int mt = 0; mt < 4; ++mt)
      #pragma unroll
      for (int r = 0; r < 4; ++r) acc[mt][r] = 0.f;
    #pragma unroll
    for (int t = 0; t < 9; ++t) {
      const int ky = t / 3, kx = t % 3;
      #pragma unroll
      for (int mt = 0; mt < 4; ++mt) {
        const int ro = (2 * mt + yoff + ky) * 448 + (xm + kx) * 40 + quad * 8;
        bf16x8 ah = *(const bf16x8*)&s3[ro];
        acc[mt] = __builtin_amdgcn_mfma_f32_16x16x32_bf16(ah, Bt[t], acc[mt], 0, 0, 0);
      }
    }
    const int ocl = lane & 15;
    #pragma unroll
    for (int mt = 0; mt < 4; ++mt) {
      float p0 = fmaxf(acc[mt][0], acc[mt][1]);
      float p1 = fmaxf(acc[mt][2], acc[mt][3]);
      p0 = fmaxf(p0, __shfl_xor(p0, 32, 64));
      p1 = fmaxf(p1, __shfl_xor(p1, 32, 64));
      if (quad < 2) {
        const int oc = nt * 16 + ocl;
        const float bias = b3[oc];
        const int base = oc * 16 + mt * 4 + (quad & 1) * 2;
        h3s[base]     = fmaxf(p0 + bias, 0.f);
        h3s[base + 1] = fmaxf(p1 + bias, 0.f);
      }
    }
  }
  __syncthreads();                       // barrier 4: h3 complete

  // ---- fc: all 4 waves, wave w handles outputs j = w, w+4, ...
  {
    float hv[16];
    #pragma unroll
    for (int i = 0; i < 16; ++i) hv[i] = h3s[i * 64 + lane];
    for (int j = w; j < 10; j += 4) {
      float dot = 0.f;
      #pragma unroll
      for (int i = 0; i < 16; ++i)
        dot = fmaf(hv[i], fcw[j * 1024 + i * 64 + lane], dot);
      #pragma unroll
      for (int s = 32; s > 0; s >>= 1) dot += __shfl_xor(dot, s, 64);
      if (lane == 0) out[img * 10 + j] = dot + fcb[j];
    }
  }
}

// -------------------------------------------------------------------- launch
extern "C" void kernel_launch(void* const* d_in, const int* in_sizes, int n_in,
                              void* d_out, int out_size, void* d_ws, size_t ws_size,
                              hipStream_t stream) {
  const float* x   = (const float*)d_in[0];
  const float* w1  = (const float*)d_in[1];
  const float* b1  = (const float*)d_in[2];
  const float* w2  = (const float*)d_in[3];
  const float* b2  = (const float*)d_in[4];
  const float* w3  = (const float*)d_in[5];
  const float* b3  = (const float*)d_in[6];
  const float* fcw = (const float*)d_in[7];
  const float* fcb = (const float*)d_in[8];
  __bf16* wsb = (__bf16*)d_ws;
  float* out = (float*)d_out;

  hipLaunchKernelGGL(pack_weights, dim3(184), dim3(256), 0, stream, w1, w2, w3, wsb);
  hipLaunchKernelGGL(cnn_fused, dim3(4096), dim3(256), 0, stream,
                     x, wsb, b1, b2, b3, fcw, fcb, out);
}

// Round 20
// 126.497 us; speedup vs baseline: 1.4077x; 1.0004x over previous
//
#include <hip/hip_runtime.h>

typedef float f32x4 __attribute__((ext_vector_type(4)));
typedef float f32x16v __attribute__((ext_vector_type(16)));
typedef __bf16 bf16x4 __attribute__((ext_vector_type(4)));
typedef __bf16 bf16x8 __attribute__((ext_vector_type(8)));

union U4B8 { uint4 u; bf16x8 b; };

// ws layout (bf16 elements): b2p[9216] @0, b3p[36864] @9216, c1p[1024] @46080
#define B2P_OFF 0
#define B3P_OFF 9216
#define C1P_OFF 46080

// ------------------------------------------------------------- pack_weights
// b2p frag f=t*2+p: lane l, j: oc=l&31, ic=(l>>5)*8+j              (32x32x16)
// b3p frag f=t*8+nt*2+p: lane l, j: oc=nt*16+(l&15), ic=(l>>4)*8+j (16x16x32)
// c1p (R19 mapping): A-frag = two horizontally-adjacent s_img cells.
__global__ __launch_bounds__(256) void pack_weights(
    const float* __restrict__ w1, const float* __restrict__ w2,
    const float* __restrict__ w3, __bf16* __restrict__ wsb) {
  int i = blockIdx.x * 256 + threadIdx.x;
  if (i < 9216) {
    int f = i >> 9, r = i & 511;
    int l = r >> 3, j = r & 7;
    int t = f >> 1, p = f & 1;
    int ky = t / 3, kx = t % 3;
    int oc = l & 31, ic = ((l >> 5) << 3) + j;
    float v = w2[oc * 144 + ic * 9 + ky * 3 + kx];
    __bf16 hi = (__bf16)v;
    wsb[B2P_OFF + i] = p ? (__bf16)(v - (float)hi) : hi;
  } else if (i < 9216 + 36864) {
    int q = i - 9216;
    int f = q >> 9, r = q & 511;
    int l = r >> 3, j = r & 7;
    int t = f >> 3, nt = (f >> 1) & 3, p = f & 1;
    int ky = t / 3, kx = t % 3;
    int oc = nt * 16 + (l & 15), ic = ((l >> 4) << 3) + j;
    float v = w3[oc * 288 + ic * 9 + ky * 3 + kx];
    __bf16 hi = (__bf16)v;
    wsb[B3P_OFF + q] = p ? (__bf16)(v - (float)hi) : hi;
  } else if (i < 9216 + 36864 + 1024) {
    int q = i - (9216 + 36864);
    int f = q >> 9, r = q & 511;
    int l = r >> 3, j = r & 7;
    int oc = l & 15, kg = l >> 4;
    int half = j >> 2, ic = j & 3;
    float v = 0.f;
    if (ic < 3) {
      if (f == 0) {
        if (kg < 3)            v = w1[oc * 27 + ic * 9 + kg * 3 + half];
        else if (half == 0)    v = w1[oc * 27 + ic * 9 + 0 * 3 + 2];
      } else {
        if (half == 0 && kg < 2) v = w1[oc * 27 + ic * 9 + (kg + 1) * 3 + 2];
      }
    }
    wsb[C1P_OFF + q] = (__bf16)v;
  }
}

// -------------------------------------------------------------- fused CNN
// R19 numerics; COMPACT overlapping LDS (16384 B -> residency cap 10 blocks
// vs R19's 5) + 2 restored barriers (R17 showed barriers cheap):
//   s_img @0 (9280B)  |  s2 @0 (16128B)  |  s3 @0 (8960B)
//   h3s @12288 (4096B, over dead s2 tail, disjoint from s3)
// fc: lane owns 16 CONTIGUOUS elements -> 4x ds_read_b128 + 4x dwordx4/j.
__global__ __launch_bounds__(256, 4) void cnn_fused(
    const float* __restrict__ x, const __bf16* __restrict__ wsb,
    const float* __restrict__ b1, const float* __restrict__ b2,
    const float* __restrict__ b3,
    const float* __restrict__ fcw, const float* __restrict__ fcb,
    float* __restrict__ out) {
  __shared__ __align__(16) unsigned char smem[16384];
  __bf16* s_img = (__bf16*)smem;
  __bf16* s2b   = (__bf16*)smem;
  __bf16* s3b   = (__bf16*)smem;
  float*  h3s   = (float*)(smem + 12288);

  const __bf16* b2p = wsb + B2P_OFF;
  const __bf16* b3p = wsb + B3P_OFF;
  const __bf16* c1p = wsb + C1P_OFF;

  const int tid = threadIdx.x;
  const int img = blockIdx.x;
  const int w = tid >> 6, lane = tid & 63;

  // ---- phase 1: halo zero (132 cells) + end pad + float4 staging
  if (tid < 132) {
    int row, col;
    if (tid < 34)       { row = 0;        col = tid; }
    else if (tid < 68)  { row = 33;       col = tid - 34; }
    else if (tid < 100) { row = tid - 67; col = 0; }
    else                { row = tid - 99; col = 33; }
    *(unsigned long long*)&s_img[(row * 34 + col) * 4] = 0ull;
  } else if (tid >= 248 && tid < 252) {
    *(unsigned long long*)&s_img[4624 + (tid - 248) * 4] = 0ull;  // pad
  }
  {
    const float* xg = x + img * 3072;
    const int r = tid * 4;
    const int y = r >> 5, xx = r & 31;
    const f32x4 c0 = *(const f32x4*)&xg[r];
    const f32x4 c1 = *(const f32x4*)&xg[r + 1024];
    const f32x4 c2 = *(const f32x4*)&xg[r + 2048];
    #pragma unroll
    for (int k = 0; k < 4; ++k) {
      bf16x4 pk;
      pk.x = (__bf16)c0[k];
      pk.y = (__bf16)c1[k];
      pk.z = (__bf16)c2[k];
      pk.w = (__bf16)0.f;
      *(bf16x4*)&s_img[((y + 1) * 34 + (xx + k + 1)) * 4] = pk;
    }
  }
  const bf16x8 B1h = *(const bf16x8*)(c1p + lane * 8);
  const bf16x8 B2h = *(const bf16x8*)(c1p + 512 + lane * 8);
  __syncthreads();                       // barrier 1: staging complete

  // ---- conv1: select-free A-build (R19-validated)
  float pooled[16];
  {
    const int xm = lane & 15, kg = lane >> 4;
    const int d1r = (kg == 3) ? 0 : kg;
    const int d1c = (kg == 3) ? 2 : 0;
    const int d2r = (kg == 0) ? 1 : 2;
    const int dd1 = d1r * 34 + d1c;
    const int dd2 = d2r * 34 + 2;
    #pragma unroll
    for (int p = 0; p < 4; ++p) {
      f32x4 acc[2][2];
      #pragma unroll
      for (int ys = 0; ys < 2; ++ys)
        #pragma unroll
        for (int xh = 0; xh < 2; ++xh)
          #pragma unroll
          for (int r = 0; r < 4; ++r) acc[ys][xh][r] = 0.f;
      #pragma unroll
      for (int ys = 0; ys < 2; ++ys) {
        const int yqg = w * 8 + p * 2 + ys;
        #pragma unroll
        for (int xh = 0; xh < 2; ++xh) {
          const int cb = yqg * 34 + xh * 16 + xm;
          const uint2 p0 = *(const uint2*)&s_img[(cb + dd1) * 4];
          const uint2 p1 = *(const uint2*)&s_img[(cb + dd1 + 1) * 4];
          const uint2 p2 = *(const uint2*)&s_img[(cb + dd2) * 4];
          const uint2 p3 = *(const uint2*)&s_img[(cb + dd2 + 1) * 4];
          U4B8 A1, A2;
          A1.u.x = p0.x; A1.u.y = p0.y; A1.u.z = p1.x; A1.u.w = p1.y;
          A2.u.x = p2.x; A2.u.y = p2.y; A2.u.z = p3.x; A2.u.w = p3.y;
          acc[ys][xh] = __builtin_amdgcn_mfma_f32_16x16x32_bf16(A1.b, B1h, acc[ys][xh], 0, 0, 0);
          acc[ys][xh] = __builtin_amdgcn_mfma_f32_16x16x32_bf16(A2.b, B2h, acc[ys][xh], 0, 0, 0);
        }
      }
      #pragma unroll
      for (int xh = 0; xh < 2; ++xh)
        #pragma unroll
        for (int xp2 = 0; xp2 < 2; ++xp2) {
          const float v0 = fmaxf(acc[0][xh][xp2 * 2], acc[0][xh][xp2 * 2 + 1]);
          const float v1 = fmaxf(acc[1][xh][xp2 * 2], acc[1][xh][xp2 * 2 + 1]);
          pooled[p * 4 + xh * 2 + xp2] = fmaxf(v0, v1);
        }
    }
  }
  __syncthreads();                       // barrier 2a: s_img dead (s2 overlays)

  // ---- h1 (bias+relu, bf16 hi only) -> s2 (row stride 448, cell 24)
  if (tid < 68) {
    int row, col;
    if (tid < 18)      { row = 0;       col = tid; }
    else if (tid < 36) { row = 17;      col = tid - 18; }
    else if (tid < 52) { row = tid - 35; col = 0; }
    else               { row = tid - 51; col = 17; }
    unsigned long long* p = (unsigned long long*)&s2b[row * 448 + col * 24];
    p[0] = 0ull; p[1] = 0ull; p[2] = 0ull; p[3] = 0ull;
  }
  {
    const int oc = lane & 15, quad = lane >> 4;
    const float bias = b1[oc];
    #pragma unroll
    for (int p = 0; p < 4; ++p)
      #pragma unroll
      for (int xh = 0; xh < 2; ++xh)
        #pragma unroll
        for (int xp2 = 0; xp2 < 2; ++xp2) {
          const float v = fmaxf(pooled[p * 4 + xh * 2 + xp2] + bias, 0.f);
          const int py = w * 4 + p, px = xh * 8 + quad * 2 + xp2;
          s2b[(py + 1) * 448 + (px + 1) * 24 + oc] = (__bf16)v;
        }
  }
  bf16x8 Bf[9];
  #pragma unroll
  for (int t = 0; t < 9; ++t)
    Bf[t] = *(const bf16x8*)(b2p + (t * 2) * 512 + lane * 8);
  __syncthreads();                       // barrier 2b: h1 complete

  // ---- conv2 (1-term), y-halves sequential
  float pooled2[8];
  {
    const unsigned short* s2 = (const unsigned short*)s2b;
    const int xm = lane & 15, yoff = (lane >> 4) & 1, kh = lane >> 5;
    #pragma unroll
    for (int i2 = 0; i2 < 2; ++i2) {
      f32x16v acc;
      #pragma unroll
      for (int r = 0; r < 16; ++r) acc[r] = 0.f;
      const int rbase = (4 * w + yoff + 2 * i2) * 448;
      #pragma unroll
      for (int t = 0; t < 9; ++t) {
        const int ky = t / 3, kx = t % 3;
        const int ro = rbase + ky * 448 + (xm + kx) * 24 + kh * 8;
        bf16x8 ah = *(const bf16x8*)&s2[ro];
        acc = __builtin_amdgcn_mfma_f32_32x32x16_bf16(ah, Bf[t], acc, 0, 0, 0);
      }
      #pragma unroll
      for (int bq = 0; bq < 2; ++bq)
        #pragma unroll
        for (int rq = 0; rq < 2; ++rq) {
          const int r0 = bq * 4 + rq * 2;
          pooled2[i2 * 4 + bq * 2 + rq] =
              fmaxf(fmaxf(acc[r0], acc[r0 + 1]), fmaxf(acc[r0 + 8], acc[r0 + 9]));
        }
    }
  }
  __syncthreads();                       // barrier 3a: s2 dead (s3 overlays)

  // ---- h2 (bias+relu, bf16 hi only) -> s3 (row stride 448, cell 40)
  if (tid < 36) {
    int row, col;
    if (tid < 10)      { row = 0;       col = tid; }
    else if (tid < 20) { row = 9;       col = tid - 10; }
    else if (tid < 28) { row = tid - 19; col = 0; }
    else               { row = tid - 27; col = 9; }
    unsigned long long* p = (unsigned long long*)&s3b[row * 448 + col * 40];
    #pragma unroll
    for (int u = 0; u < 8; ++u) p[u] = 0ull;
  }
  {
    const int oc = lane & 31, hh = lane >> 5;
    const float bias = b2[oc];
    #pragma unroll
    for (int i2 = 0; i2 < 2; ++i2)
      #pragma unroll
      for (int bq = 0; bq < 2; ++bq)
        #pragma unroll
        for (int rq = 0; rq < 2; ++rq) {
          const float v = fmaxf(pooled2[i2 * 4 + bq * 2 + rq] + bias, 0.f);
          const int py = 2 * w + i2, px = 2 * hh + 4 * bq + rq;
          s3b[(py + 1) * 448 + (px + 1) * 40 + oc] = (__bf16)v;
        }
  }
  __syncthreads();                       // barrier 3b: h2 complete

  // ---- conv3 (wave = nt = oc-tile), 1-term; h3s (@12288) disjoint from s3
  {
    const unsigned short* s3 = (const unsigned short*)s3b;
    const int nt = w;
    bf16x8 Bt[9];
    #pragma unroll
    for (int t = 0; t < 9; ++t)
      Bt[t] = *(const bf16x8*)(b3p + (t * 8 + nt * 2) * 512 + lane * 8);
    const int m = lane & 15, quad = lane >> 4;
    const int xm = m & 7, yoff = m >> 3;
    f32x4 acc[4];
    #pragma unroll
    for (int mt = 0; mt < 4; ++mt)
      #pragma unroll
      for (int r = 0; r < 4; ++r) acc[mt][r] = 0.f;
    #pragma unroll
    for (int t = 0; t < 9; ++t) {
      const int ky = t / 3, kx = t % 3;
      #pragma unroll
      for (int mt = 0; mt < 4; ++mt) {
        const int ro = (2 * mt + yoff + ky) * 448 + (xm + kx) * 40 + quad * 8;
        bf16x8 ah = *(const bf16x8*)&s3[ro];
        acc[mt] = __builtin_amdgcn_mfma_f32_16x16x32_bf16(ah, Bt[t], acc[mt], 0, 0, 0);
      }
    }
    const int ocl = lane & 15;
    #pragma unroll
    for (int mt = 0; mt < 4; ++mt) {
      float p0 = fmaxf(acc[mt][0], acc[mt][1]);
      float p1 = fmaxf(acc[mt][2], acc[mt][3]);
      p0 = fmaxf(p0, __shfl_xor(p0, 32, 64));
      p1 = fmaxf(p1, __shfl_xor(p1, 32, 64));
      if (quad < 2) {
        const int oc = nt * 16 + ocl;
        const float bias = b3[oc];
        const int base = oc * 16 + mt * 4 + (quad & 1) * 2;
        h3s[base]     = fmaxf(p0 + bias, 0.f);
        h3s[base + 1] = fmaxf(p1 + bias, 0.f);
      }
    }
  }
  __syncthreads();                       // barrier 4: h3 complete

  // ---- fc: lane owns 16 contiguous elements; 4x b128 LDS + 4x dwordx4/j
  {
    f32x4 hv[4];
    #pragma unroll
    for (int k = 0; k < 4; ++k) hv[k] = *(const f32x4*)&h3s[lane * 16 + k * 4];
    for (int j = w; j < 10; j += 4) {
      const f32x4* fw4 = (const f32x4*)&fcw[j * 1024 + lane * 16];
      float dot = 0.f;
      #pragma unroll
      for (int k = 0; k < 4; ++k) {
        const f32x4 fv = fw4[k];
        dot = fmaf(hv[k][0], fv[0], dot);
        dot = fmaf(hv[k][1], fv[1], dot);
        dot = fmaf(hv[k][2], fv[2], dot);
        dot = fmaf(hv[k][3], fv[3], dot);
      }
      #pragma unroll
      for (int s = 32; s > 0; s >>= 1) dot += __shfl_xor(dot, s, 64);
      if (lane == 0) out[img * 10 + j] = dot + fcb[j];
    }
  }
}

// -------------------------------------------------------------------- launch
extern "C" void kernel_launch(void* const* d_in, const int* in_sizes, int n_in,
                              void* d_out, int out_size, void* d_ws, size_t ws_size,
                              hipStream_t stream) {
  const float* x   = (const float*)d_in[0];
  const float* w1  = (const float*)d_in[1];
  const float* b1  = (const float*)d_in[2];
  const float* w2  = (const float*)d_in[3];
  const float* b2  = (const float*)d_in[4];
  const float* w3  = (const float*)d_in[5];
  const float* b3  = (const float*)d_in[6];
  const float* fcw = (const float*)d_in[7];
  const float* fcb = (const float*)d_in[8];
  __bf16* wsb = (__bf16*)d_ws;
  float* out = (float*)d_out;

  hipLaunchKernelGGL(pack_weights, dim3(184), dim3(256), 0, stream, w1, w2, w3, wsb);
  hipLaunchKernelGGL(cnn_fused, dim3(4096), dim3(256), 0, stream,
                     x, wsb, b1, b2, b3, fcw, fcb, out);
}